// Round 1
// baseline (751.884 us; speedup 1.0000x reference)
//
#include <hip/hip_runtime.h>
#include <cmath>

#define E_ 256
#define H_ 8
#define DH 32
#define MLPD 1024
#define LATD 128
#define TOPK_ 32
#define BB 2
#define RR 1024
#define CC 4
#define NT 8192      // B*R*C tokens
#define BF 8         // B*C
#define SPLIT 768

// ---------------------------------------------------------------------------
// Generic f32 GEMM: C[M][N] = A(MxK,row) @ B(NxK,row)^T  (+bias)(+gelu)(+res)
// AMAP: 0 linear A rows; 1 train-row map (m -> (m/768)*1024 + m%768)
// OMAP: 0 linear out rows; 1 st-row -> BRCE token row
// ---------------------------------------------------------------------------
template<int BIAS, int GELU, int RES, int AMAP, int OMAP>
__global__ __launch_bounds__(256) void gemm_abt(
    const float* __restrict__ A, const float* __restrict__ Bw,
    const float* __restrict__ bias, const float* __restrict__ res,
    float* __restrict__ Cc, int M, int N, int K)
{
    __shared__ float As[16][72];
    __shared__ float Bs[16][72];
    const int tid = threadIdx.x;
    const int tx = tid & 15, ty = tid >> 4;
    const int n0 = blockIdx.x * 64, m0 = blockIdx.y * 64;

    const int lr = tid >> 2;         // 0..63
    const int lk = (tid & 3) * 4;    // 0,4,8,12

    int am = m0 + lr;
    size_t arow = (AMAP == 1) ? ((size_t)(am / SPLIT) * RR + (am % SPLIT)) : (size_t)am;

    const float* Aptr = A + arow * (size_t)K + lk;
    const float* Bptr = Bw + (size_t)(n0 + lr) * K + lk;

    float acc[4][4];
#pragma unroll
    for (int i = 0; i < 4; i++)
#pragma unroll
        for (int j = 0; j < 4; j++) acc[i][j] = 0.f;

    for (int k0 = 0; k0 < K; k0 += 16) {
        float4 av = *(const float4*)(Aptr + k0);
        float4 bv = *(const float4*)(Bptr + k0);
        As[lk + 0][lr] = av.x; As[lk + 1][lr] = av.y; As[lk + 2][lr] = av.z; As[lk + 3][lr] = av.w;
        Bs[lk + 0][lr] = bv.x; Bs[lk + 1][lr] = bv.y; Bs[lk + 2][lr] = bv.z; Bs[lk + 3][lr] = bv.w;
        __syncthreads();
#pragma unroll
        for (int kk = 0; kk < 16; kk++) {
            float4 a = *(const float4*)&As[kk][ty * 4];
            float4 b = *(const float4*)&Bs[kk][tx * 4];
            float af[4] = {a.x, a.y, a.z, a.w};
            float bf[4] = {b.x, b.y, b.z, b.w};
#pragma unroll
            for (int i = 0; i < 4; i++)
#pragma unroll
                for (int j = 0; j < 4; j++) acc[i][j] += af[i] * bf[j];
        }
        __syncthreads();
    }

#pragma unroll
    for (int i = 0; i < 4; i++) {
        int row = m0 + ty * 4 + i;
        size_t orow;
        if (OMAP == 1) {
            int bc = row >> 10, r = row & 1023;
            int b = bc >> 2, c = bc & 3;
            orow = ((size_t)(b * RR + r)) * CC + c;
        } else orow = (size_t)row;
        float vv[4];
#pragma unroll
        for (int j = 0; j < 4; j++) {
            int col = n0 + tx * 4 + j;
            float v = acc[i][j];
            if (BIAS) v += bias[col];
            if (GELU) v = 0.5f * v * (1.0f + erff(v * 0.70710678118654752f));
            if (RES)  v += res[(size_t)row * N + col];
            vv[j] = v;
        }
        float4 o; o.x = vv[0]; o.y = vv[1]; o.z = vv[2]; o.w = vv[3];
        *(float4*)(Cc + orow * (size_t)N + n0 + tx * 4) = o;
    }
}

// ---------------------------------------------------------------------------
// Feature attention: seq len 4, per (b,r) block. Reads qkv (8192x768).
// ---------------------------------------------------------------------------
__global__ __launch_bounds__(256) void fa_attn(const float* __restrict__ qkv,
                                               float* __restrict__ outb)
{
    int seq = blockIdx.x, tid = threadIdx.x;
    __shared__ float sq[4][E_], sk[4][E_], sv[4][E_];
    __shared__ float ss[H_][4][4];
    __shared__ float sw[H_][4][4];
    for (int i = 0; i < 4; i++) {
        const float* srcp = qkv + ((size_t)(seq * 4 + i)) * 768;
        for (int idx = tid; idx < 768; idx += 256) {
            float v = srcp[idx];
            if (idx < 256) sq[i][idx] = v;
            else if (idx < 512) sk[i][idx - 256] = v;
            else sv[i][idx - 512] = v;
        }
    }
    __syncthreads();
    if (tid < 128) {
        int h = tid >> 4, i = (tid >> 2) & 3, j = tid & 3;
        float s = 0;
        for (int d = 0; d < DH; d++) s += sq[i][h * DH + d] * sk[j][h * DH + d];
        ss[h][i][j] = s * 0.17677669529663688f;   // 1/sqrt(32)
    }
    __syncthreads();
    if (tid < 32) {
        int h = tid >> 2, i = tid & 3;
        float m = ss[h][i][0];
        for (int j = 1; j < 4; j++) m = fmaxf(m, ss[h][i][j]);
        float e[4], sum = 0;
        for (int j = 0; j < 4; j++) { e[j] = expf(ss[h][i][j] - m); sum += e[j]; }
        float inv = 1.0f / sum;
        for (int j = 0; j < 4; j++) sw[h][i][j] = e[j] * inv;
    }
    __syncthreads();
    int e = tid, h = e >> 5;
    for (int i = 0; i < 4; i++) {
        float o = 0;
        for (int j = 0; j < 4; j++) o += sw[h][i][j] * sv[j][e];
        outb[((size_t)(seq * 4 + i)) * E_ + e] = o;
    }
}

// ---------------------------------------------------------------------------
// LayerNorm per 256-wide row. OMAP=1: write token row -> st row (transpose).
// ---------------------------------------------------------------------------
template<int OMAP>
__global__ __launch_bounds__(64) void ln_k(const float* __restrict__ in,
                                           const float* __restrict__ g,
                                           const float* __restrict__ bta,
                                           float* __restrict__ out)
{
    int row = blockIdx.x, t = threadIdx.x;
    float4 v = ((const float4*)(in + (size_t)row * E_))[t];
    float s = v.x + v.y + v.z + v.w;
#pragma unroll
    for (int o = 32; o >= 1; o >>= 1) s += __shfl_xor(s, o);
    float mean = s * (1.0f / E_);
    float dx0 = v.x - mean, dx1 = v.y - mean, dx2 = v.z - mean, dx3 = v.w - mean;
    float q = dx0 * dx0 + dx1 * dx1 + dx2 * dx2 + dx3 * dx3;
#pragma unroll
    for (int o = 32; o >= 1; o >>= 1) q += __shfl_xor(q, o);
    float inv = rsqrtf(q * (1.0f / E_) + 1e-5f);
    size_t orow;
    if (OMAP == 1) {
        int b = row >> 12, r = (row >> 2) & 1023, c = row & 3;
        orow = ((size_t)(b * CC + c)) * RR + r;
    } else orow = (size_t)row;
    int c0 = t * 4;
    float4 o;
    o.x = dx0 * inv * g[c0 + 0] + bta[c0 + 0];
    o.y = dx1 * inv * g[c0 + 1] + bta[c0 + 1];
    o.z = dx2 * inv * g[c0 + 2] + bta[c0 + 2];
    o.w = dx3 * inv * g[c0 + 3] + bta[c0 + 3];
    ((float4*)(out + orow * E_))[t] = o;
}

// ---------------------------------------------------------------------------
// Indexer projections: q32 / k32 = st_row @ {idx_q_w, idx_k_w}^T  (32 each)
// ---------------------------------------------------------------------------
__global__ __launch_bounds__(256) void idx_proj(const float* __restrict__ st,
                                                const float* __restrict__ qw,
                                                const float* __restrict__ kw,
                                                float* __restrict__ q32,
                                                float* __restrict__ k32)
{
    int row = blockIdx.x, tid = threadIdx.x;
    __shared__ float sx[E_];
    sx[tid] = st[(size_t)row * E_ + tid];
    __syncthreads();
    int d = tid >> 2, sub = tid & 3;
    const float* w = (d < 32) ? (qw + (size_t)d * E_) : (kw + (size_t)(d - 32) * E_);
    float s = 0;
    for (int k = sub; k < E_; k += 4) s += w[k] * sx[k];
    s += __shfl_xor(s, 1); s += __shfl_xor(s, 2);
    if (sub == 0) {
        if (d < 32) q32[(size_t)row * 32 + d] = s;
        else        k32[(size_t)row * 32 + (d - 32)] = s;
    }
}

// ---------------------------------------------------------------------------
// Indexer scales: 96 blocks = type(0 q-train,1 q-test,2 k-train) x bf x h
// scale = (max|.| + 1e-6)/127
// ---------------------------------------------------------------------------
__global__ __launch_bounds__(256) void idx_scales(const float* __restrict__ q32,
                                                  const float* __restrict__ k32,
                                                  float* __restrict__ scl)
{
    int id = blockIdx.x;
    int type = id / 32, bf = (id % 32) >> 2, h = id & 3;
    const float* src = (type == 2) ? k32 : q32;
    int r0 = (type == 1) ? SPLIT : 0;
    int r1 = (type == 1) ? RR : SPLIT;
    float m = 0;
    for (int r = r0 + (int)threadIdx.x; r < r1; r += 256) {
        const float* p = src + ((size_t)(bf * RR + r)) * 32 + h * 8;
        for (int dd = 0; dd < 8; dd++) m = fmaxf(m, fabsf(p[dd]));
    }
#pragma unroll
    for (int o = 32; o >= 1; o >>= 1) m = fmaxf(m, __shfl_xor(m, o));
    __shared__ float red[4];
    if ((threadIdx.x & 63) == 0) red[threadIdx.x >> 6] = m;
    __syncthreads();
    if (threadIdx.x == 0) {
        m = fmaxf(fmaxf(red[0], red[1]), fmaxf(red[2], red[3]));
        scl[id] = (m + 1e-6f) / 127.0f;
    }
}

// ---------------------------------------------------------------------------
// Quantize k (train rows only) to int8
// ---------------------------------------------------------------------------
__global__ __launch_bounds__(256) void idx_quantk(const float* __restrict__ k32,
                                                  const float* __restrict__ scl,
                                                  signed char* __restrict__ ki8)
{
    int gi = blockIdx.x * 256 + threadIdx.x;     // 0 .. 8*768*32-1
    int bf = gi / (SPLIT * 32);
    int rem = gi % (SPLIT * 32);
    int r = rem >> 5, d = rem & 31, h = d >> 3;
    float ks = scl[64 + bf * 4 + h];
    float v = k32[((size_t)(bf * RR + r)) * 32 + d];
    float qq = fminf(fmaxf(rintf(v / ks), -127.f), 127.f);
    ki8[gi] = (signed char)qq;
}

// ---------------------------------------------------------------------------
// Indexer scores + top-32 (ties -> smallest index, matching jax.lax.top_k)
// ---------------------------------------------------------------------------
__global__ __launch_bounds__(256) void idx_score_topk(const float* __restrict__ q32,
                                                      const signed char* __restrict__ ki8,
                                                      const float* __restrict__ scl,
                                                      const float* __restrict__ ow,
                                                      int* __restrict__ idx_out)
{
    int bid = blockIdx.x, tid = threadIdx.x;
    int bf = bid >> 10, qr = bid & 1023;
    int sel = (qr < SPLIT) ? 0 : 32;
    __shared__ float qi[32];
    __shared__ float fac[4];
    __shared__ float red[SPLIT];
    __shared__ float bv[4];
    __shared__ int bi[4];
    if (tid < 32) {
        int h = tid >> 3;
        float qs = scl[sel + bf * 4 + h];
        float v = q32[((size_t)bid) * 32 + tid];
        qi[tid] = fminf(fmaxf(rintf(v / qs), -127.f), 127.f);
    }
    if (tid < 4) {
        float qs = scl[sel + bf * 4 + tid];
        float ks = scl[64 + bf * 4 + tid];
        fac[tid] = __fmul_rn(qs, ks);
    }
    __syncthreads();
    for (int k = tid; k < SPLIT; k += 256) {
        const signed char* kp = ki8 + ((size_t)(bf * SPLIT + k)) * 32;
        float r = 0;
#pragma unroll
        for (int h = 0; h < 4; h++) {
            float dot = 0;
#pragma unroll
            for (int dd = 0; dd < 8; dd++)
                dot = __fadd_rn(dot, __fmul_rn(qi[h * 8 + dd], (float)kp[h * 8 + dd]));
            float sc = fmaxf(__fmul_rn(dot, fac[h]), 0.f);
            r = __fadd_rn(r, __fmul_rn(sc, ow[h]));
        }
        red[k] = r;
    }
    __syncthreads();
    for (int it = 0; it < TOPK_; it++) {
        float best = -3.0e38f; int besti = 0x7fffffff;
        for (int k = tid; k < SPLIT; k += 256) {
            float v = red[k];
            if (v > best || (v == best && k < besti)) { best = v; besti = k; }
        }
#pragma unroll
        for (int o = 1; o < 64; o <<= 1) {
            float ov = __shfl_xor(best, o);
            int oi = __shfl_xor(besti, o);
            if (ov > best || (ov == best && oi < besti)) { best = ov; besti = oi; }
        }
        if ((tid & 63) == 0) { bv[tid >> 6] = best; bi[tid >> 6] = besti; }
        __syncthreads();
        if (tid == 0) {
            for (int w = 1; w < 4; w++)
                if (bv[w] > best || (bv[w] == best && bi[w] < besti)) { best = bv[w]; besti = bi[w]; }
            idx_out[(size_t)bid * TOPK_ + it] = besti;
            red[besti] = -3.0e38f;
        }
        __syncthreads();
    }
}

// ---------------------------------------------------------------------------
// MLA absorption part 1: G[q][h][l] = sum_d qbuf[q][h*32+d] * up_w[h*32+d][l]
// grid (128 qtiles, 8 heads)
// ---------------------------------------------------------------------------
__global__ __launch_bounds__(256) void mla_g(const float* __restrict__ qb,
                                             const float* __restrict__ uw,
                                             float* __restrict__ G)
{
    int qt = blockIdx.x, h = blockIdx.y, tid = threadIdx.x;
    __shared__ float Qs[64][33];
    __shared__ float Us[32][132];
    {
        int r = tid >> 2, c0 = (tid & 3) * 8;
        const float* srcp = qb + ((size_t)(qt * 64 + r)) * E_ + h * DH + c0;
        float4 a = ((const float4*)srcp)[0];
        float4 b = ((const float4*)srcp)[1];
        Qs[r][c0 + 0] = a.x; Qs[r][c0 + 1] = a.y; Qs[r][c0 + 2] = a.z; Qs[r][c0 + 3] = a.w;
        Qs[r][c0 + 4] = b.x; Qs[r][c0 + 5] = b.y; Qs[r][c0 + 6] = b.z; Qs[r][c0 + 7] = b.w;
    }
    {
        int d = tid >> 3, l0 = (tid & 7) * 16;
        const float* srcp = uw + (size_t)(h * DH + d) * LATD + l0;
#pragma unroll
        for (int ii = 0; ii < 4; ii++) {
            float4 v = ((const float4*)srcp)[ii];
            *(float4*)&Us[d][l0 + ii * 4] = v;
        }
    }
    __syncthreads();
    int rg = tid >> 5, l = (tid & 31) * 4;
    float acc[8][4];
#pragma unroll
    for (int i = 0; i < 8; i++)
#pragma unroll
        for (int j = 0; j < 4; j++) acc[i][j] = 0.f;
    for (int d = 0; d < DH; d++) {
        float4 u = *(const float4*)&Us[d][l];
#pragma unroll
        for (int i = 0; i < 8; i++) {
            float qv = Qs[rg * 8 + i][d];
            acc[i][0] += qv * u.x; acc[i][1] += qv * u.y;
            acc[i][2] += qv * u.z; acc[i][3] += qv * u.w;
        }
    }
#pragma unroll
    for (int i = 0; i < 8; i++) {
        float4 o = {acc[i][0], acc[i][1], acc[i][2], acc[i][3]};
        *(float4*)(G + ((size_t)(qt * 64 + rg * 8 + i)) * 1024 + h * 128 + l) = o;
    }
}

// ---------------------------------------------------------------------------
// Fused sparse MLA attention per (bf, q): scores from G . c_sel, softmax,
// M[h][l] = sum_j w[j][h] * c_sel[j][l]
// ---------------------------------------------------------------------------
__global__ __launch_bounds__(256) void mla_attn(const float* __restrict__ G,
                                                const float* __restrict__ cb,
                                                const int* __restrict__ idxb,
                                                float* __restrict__ Mo)
{
    int bid = blockIdx.x, tid = threadIdx.x;
    int bf = bid >> 10;
    __shared__ float cs[32][132];
    __shared__ float gs[8][132];
    __shared__ float swt[32][8];
    __shared__ int sidx[32];
    if (tid < 32) sidx[tid] = idxb[(size_t)bid * 32 + tid];
    {
        int flat = tid * 4, h = flat >> 7, l = flat & 127;
        float4 gv = *(const float4*)(G + (size_t)bid * 1024 + flat);
        *(float4*)&gs[h][l] = gv;
    }
    __syncthreads();
    {
        int j = tid >> 3, l0 = (tid & 7) * 16;
        const float* srcp = cb + ((size_t)(bf * SPLIT + sidx[j])) * LATD + l0;
#pragma unroll
        for (int ii = 0; ii < 4; ii++) {
            float4 vv = ((const float4*)srcp)[ii];
            *(float4*)&cs[j][l0 + ii * 4] = vv;
        }
    }
    __syncthreads();
    {
        int j = tid >> 3, h = tid & 7;
        float s = 0;
#pragma unroll
        for (int lb = 0; lb < 32; lb++) {
            float4 c4 = *(const float4*)&cs[j][lb * 4];
            float4 g4 = *(const float4*)&gs[h][lb * 4];
            s += c4.x * g4.x + c4.y * g4.y + c4.z * g4.z + c4.w * g4.w;
        }
        swt[j][h] = s * 0.17677669529663688f;
    }
    __syncthreads();
    if (tid < 8) {
        float m = swt[0][tid];
        for (int j = 1; j < 32; j++) m = fmaxf(m, swt[j][tid]);
        float sum = 0;
        for (int j = 0; j < 32; j++) { float e = expf(swt[j][tid] - m); swt[j][tid] = e; sum += e; }
        float inv = 1.0f / sum;
        for (int j = 0; j < 32; j++) swt[j][tid] *= inv;
    }
    __syncthreads();
    {
        int flat = tid * 4, h = flat >> 7, l = flat & 127;
        float4 acc = {0, 0, 0, 0};
        for (int j = 0; j < 32; j++) {
            float w = swt[j][h];
            float4 c4 = *(const float4*)&cs[j][l];
            acc.x += w * c4.x; acc.y += w * c4.y; acc.z += w * c4.z; acc.w += w * c4.w;
        }
        *(float4*)(Mo + (size_t)bid * 1024 + flat) = acc;
    }
}

// ---------------------------------------------------------------------------
// MLA absorption part 2: out[q][h*32+d] = sum_l M[q][h][l] * up_w[256+h*32+d][l]
// ---------------------------------------------------------------------------
__global__ __launch_bounds__(256) void mla_out(const float* __restrict__ Mo,
                                               const float* __restrict__ uw,
                                               float* __restrict__ ob)
{
    int qt = blockIdx.x, h = blockIdx.y, tid = threadIdx.x;
    __shared__ float Ms[64][132];
    __shared__ float Us[32][129];
    {
        int r = tid >> 2, l0 = (tid & 3) * 32;
        const float* srcp = Mo + ((size_t)(qt * 64 + r)) * 1024 + h * 128 + l0;
#pragma unroll
        for (int ii = 0; ii < 8; ii++) {
            float4 v = ((const float4*)srcp)[ii];
            *(float4*)&Ms[r][l0 + ii * 4] = v;
        }
    }
    {
        int d = tid >> 3, l0 = (tid & 7) * 16;
        const float* srcp = uw + (size_t)(256 + h * DH + d) * LATD + l0;
#pragma unroll
        for (int ii = 0; ii < 4; ii++) {
            float4 v = ((const float4*)srcp)[ii];
            Us[d][l0 + ii * 4 + 0] = v.x; Us[d][l0 + ii * 4 + 1] = v.y;
            Us[d][l0 + ii * 4 + 2] = v.z; Us[d][l0 + ii * 4 + 3] = v.w;
        }
    }
    __syncthreads();
    int d = tid & 31, rg = tid >> 5;
    float acc[8] = {0, 0, 0, 0, 0, 0, 0, 0};
    for (int l = 0; l < 128; l++) {
        float u = Us[d][l];
#pragma unroll
        for (int i = 0; i < 8; i++) acc[i] += Ms[rg * 8 + i][l] * u;
    }
#pragma unroll
    for (int i = 0; i < 8; i++)
        ob[((size_t)(qt * 64 + rg * 8 + i)) * E_ + h * DH + d] = acc[i];
}

// ---------------------------------------------------------------------------
extern "C" void kernel_launch(void* const* d_in, const int* in_sizes, int n_in,
                              void* d_out, int out_size, void* d_ws, size_t ws_size,
                              hipStream_t stream)
{
    (void)in_sizes; (void)n_in; (void)out_size; (void)ws_size;
    const float* src      = (const float*)d_in[0];
    // d_in[1] = train_test_split_index (always 768 in this dataset)
    const float* fa_in_w  = (const float*)d_in[2];
    const float* fa_in_b  = (const float*)d_in[3];
    const float* fa_out_w = (const float*)d_in[4];
    const float* fa_out_b = (const float*)d_in[5];
    const float* n1g = (const float*)d_in[6];
    const float* n1b = (const float*)d_in[7];
    const float* iqw = (const float*)d_in[8];
    const float* ikw = (const float*)d_in[9];
    const float* iow = (const float*)d_in[10];
    const float* mqw = (const float*)d_in[11];
    const float* mdw = (const float*)d_in[12];
    const float* muw = (const float*)d_in[13];
    const float* mow = (const float*)d_in[14];
    const float* n2g = (const float*)d_in[15];
    const float* n2b = (const float*)d_in[16];
    const float* l1w = (const float*)d_in[17];
    const float* l1b = (const float*)d_in[18];
    const float* l2w = (const float*)d_in[19];
    const float* l2b = (const float*)d_in[20];
    const float* n3g = (const float*)d_in[21];
    const float* n3b = (const float*)d_in[22];

    float* ws = (float*)d_ws;
    size_t off = 0;
    float* ws0  = ws + off; off += (size_t)NT * 1024;   // qkv -> G -> h1
    float* ws1  = ws + off; off += (size_t)NT * 1024;   // M
    float* abuf = ws + off; off += (size_t)NT * E_;     // attn-out -> mla_q -> mla-attn-out
    float* stb  = ws + off; off += (size_t)NT * E_;     // st (post-LN1, transposed layout)
    float* tbuf = ws + off; off += (size_t)NT * E_;     // pre-LN1 -> pre-LN2 -> pre-LN3
    float* x2   = ws + off; off += (size_t)NT * E_;     // LN2 out (MLP residual)
    float* q32  = ws + off; off += (size_t)NT * 32;
    float* k32  = ws + off; off += (size_t)NT * 32;
    float* scl  = ws + off; off += 128;
    float* cb   = ws + off; off += (size_t)BF * SPLIT * LATD;
    int*   idxb = (int*)(ws + off); off += (size_t)NT * 32;
    signed char* ki8 = (signed char*)(ws + off); off += (size_t)NT * 32 / 4;

    dim3 blk(256);
    // 1. qkv = src @ fa_in_w^T + b
    gemm_abt<1,0,0,0,0><<<dim3(12,128), blk, 0, stream>>>(src, fa_in_w, fa_in_b, nullptr, ws0, NT, 768, 256);
    // 2. feature attention (S=4)
    fa_attn<<<2048, blk, 0, stream>>>(ws0, abuf);
    // 3. out-proj + bias + residual(src)
    gemm_abt<1,0,1,0,0><<<dim3(4,128), blk, 0, stream>>>(abuf, fa_out_w, fa_out_b, src, tbuf, NT, 256, 256);
    // 4. LN1, write transposed (token -> st row)
    ln_k<1><<<NT, dim3(64), 0, stream>>>(tbuf, n1g, n1b, stb);
    // 5. indexer projections
    idx_proj<<<NT, blk, 0, stream>>>(stb, iqw, ikw, q32, k32);
    // 6. scales
    idx_scales<<<96, blk, 0, stream>>>(q32, k32, scl);
    // 7. quantize k
    idx_quantk<<<(BF*SPLIT*32)/256, blk, 0, stream>>>(k32, scl, ki8);
    // 8. scores + top-32
    idx_score_topk<<<NT, blk, 0, stream>>>(q32, ki8, scl, iow, idxb);
    // 9. c = x_tr @ down_w^T   (train rows only)
    gemm_abt<0,0,0,1,0><<<dim3(2,96), blk, 0, stream>>>(stb, mdw, nullptr, nullptr, cb, BF*SPLIT, LATD, 256);
    // 10. mla q projection
    gemm_abt<0,0,0,0,0><<<dim3(4,128), blk, 0, stream>>>(stb, mqw, nullptr, nullptr, abuf, NT, 256, 256);
    // 11. G = per-head up_w(K-half)^T @ q
    mla_g<<<dim3(128,8), blk, 0, stream>>>(abuf, muw, ws0);
    // 12. fused sparse attention -> M
    mla_attn<<<NT, blk, 0, stream>>>(ws0, cb, idxb, ws1);
    // 13. out = per-head up_w(V-half) @ M
    mla_out<<<dim3(128,8), blk, 0, stream>>>(ws1, muw, abuf);
    // 14. mla out-proj + residual(st), write transposed back to BRCE
    gemm_abt<0,0,1,0,1><<<dim3(4,128), blk, 0, stream>>>(abuf, mow, nullptr, stb, tbuf, NT, 256, 256);
    // 15. LN2
    ln_k<0><<<NT, dim3(64), 0, stream>>>(tbuf, n2g, n2b, x2);
    // 16. MLP1 + GELU
    gemm_abt<1,1,0,0,0><<<dim3(16,128), blk, 0, stream>>>(x2, l1w, l1b, nullptr, ws0, NT, MLPD, 256);
    // 17. MLP2 + bias + residual(x2)
    gemm_abt<1,0,1,0,0><<<dim3(4,128), blk, 0, stream>>>(ws0, l2w, l2b, x2, tbuf, NT, 256, MLPD);
    // 18. LN3 -> output
    ln_k<0><<<NT, dim3(64), 0, stream>>>(tbuf, n3g, n3b, (float*)d_out);
}

// Round 2
// 694.202 us; speedup vs baseline: 1.0831x; 1.0831x over previous
//
#include <hip/hip_runtime.h>
#include <cmath>

#define E_ 256
#define H_ 8
#define DH 32
#define MLPD 1024
#define LATD 128
#define TOPK_ 32
#define BB 2
#define RR 1024
#define CC 4
#define NT 8192      // B*R*C tokens
#define BF 8         // B*C
#define SPLIT 768

// ---------------------------------------------------------------------------
// Generic f32 GEMM: C[M][N] = A(MxK,row) @ B(NxK,row)^T  (+bias)(+gelu)(+res)
// AMAP: 0 linear A rows; 1 train-row map (m -> (m/768)*1024 + m%768)
// OMAP: 0 linear out rows; 1 st-row -> BRCE token row
// ---------------------------------------------------------------------------
template<int BIAS, int GELU, int RES, int AMAP, int OMAP>
__global__ __launch_bounds__(256) void gemm_abt(
    const float* __restrict__ A, const float* __restrict__ Bw,
    const float* __restrict__ bias, const float* __restrict__ res,
    float* __restrict__ Cc, int M, int N, int K)
{
    __shared__ float As[16][72];
    __shared__ float Bs[16][72];
    const int tid = threadIdx.x;
    const int tx = tid & 15, ty = tid >> 4;
    const int n0 = blockIdx.x * 64, m0 = blockIdx.y * 64;

    const int lr = tid >> 2;         // 0..63
    const int lk = (tid & 3) * 4;    // 0,4,8,12

    int am = m0 + lr;
    size_t arow = (AMAP == 1) ? ((size_t)(am / SPLIT) * RR + (am % SPLIT)) : (size_t)am;

    const float* Aptr = A + arow * (size_t)K + lk;
    const float* Bptr = Bw + (size_t)(n0 + lr) * K + lk;

    float acc[4][4];
#pragma unroll
    for (int i = 0; i < 4; i++)
#pragma unroll
        for (int j = 0; j < 4; j++) acc[i][j] = 0.f;

    for (int k0 = 0; k0 < K; k0 += 16) {
        float4 av = *(const float4*)(Aptr + k0);
        float4 bv = *(const float4*)(Bptr + k0);
        As[lk + 0][lr] = av.x; As[lk + 1][lr] = av.y; As[lk + 2][lr] = av.z; As[lk + 3][lr] = av.w;
        Bs[lk + 0][lr] = bv.x; Bs[lk + 1][lr] = bv.y; Bs[lk + 2][lr] = bv.z; Bs[lk + 3][lr] = bv.w;
        __syncthreads();
#pragma unroll
        for (int kk = 0; kk < 16; kk++) {
            float4 a = *(const float4*)&As[kk][ty * 4];
            float4 b = *(const float4*)&Bs[kk][tx * 4];
            float af[4] = {a.x, a.y, a.z, a.w};
            float bf[4] = {b.x, b.y, b.z, b.w};
#pragma unroll
            for (int i = 0; i < 4; i++)
#pragma unroll
                for (int j = 0; j < 4; j++) acc[i][j] += af[i] * bf[j];
        }
        __syncthreads();
    }

#pragma unroll
    for (int i = 0; i < 4; i++) {
        int row = m0 + ty * 4 + i;
        size_t orow;
        if (OMAP == 1) {
            int bc = row >> 10, r = row & 1023;
            int b = bc >> 2, c = bc & 3;
            orow = ((size_t)(b * RR + r)) * CC + c;
        } else orow = (size_t)row;
        float vv[4];
#pragma unroll
        for (int j = 0; j < 4; j++) {
            int col = n0 + tx * 4 + j;
            float v = acc[i][j];
            if (BIAS) v += bias[col];
            if (GELU) v = 0.5f * v * (1.0f + erff(v * 0.70710678118654752f));
            if (RES)  v += res[(size_t)row * N + col];
            vv[j] = v;
        }
        float4 o; o.x = vv[0]; o.y = vv[1]; o.z = vv[2]; o.w = vv[3];
        *(float4*)(Cc + orow * (size_t)N + n0 + tx * 4) = o;
    }
}

// ---------------------------------------------------------------------------
// Feature attention: seq len 4, per (b,r) block. Reads qkv (8192x768).
// ---------------------------------------------------------------------------
__global__ __launch_bounds__(256) void fa_attn(const float* __restrict__ qkv,
                                               float* __restrict__ outb)
{
    int seq = blockIdx.x, tid = threadIdx.x;
    __shared__ float sq[4][E_], sk[4][E_], sv[4][E_];
    __shared__ float ss[H_][4][4];
    __shared__ float sw[H_][4][4];
    for (int i = 0; i < 4; i++) {
        const float* srcp = qkv + ((size_t)(seq * 4 + i)) * 768;
        for (int idx = tid; idx < 768; idx += 256) {
            float v = srcp[idx];
            if (idx < 256) sq[i][idx] = v;
            else if (idx < 512) sk[i][idx - 256] = v;
            else sv[i][idx - 512] = v;
        }
    }
    __syncthreads();
    if (tid < 128) {
        int h = tid >> 4, i = (tid >> 2) & 3, j = tid & 3;
        float s = 0;
        for (int d = 0; d < DH; d++) s += sq[i][h * DH + d] * sk[j][h * DH + d];
        ss[h][i][j] = s * 0.17677669529663688f;   // 1/sqrt(32)
    }
    __syncthreads();
    if (tid < 32) {
        int h = tid >> 2, i = tid & 3;
        float m = ss[h][i][0];
        for (int j = 1; j < 4; j++) m = fmaxf(m, ss[h][i][j]);
        float e[4], sum = 0;
        for (int j = 0; j < 4; j++) { e[j] = expf(ss[h][i][j] - m); sum += e[j]; }
        float inv = 1.0f / sum;
        for (int j = 0; j < 4; j++) sw[h][i][j] = e[j] * inv;
    }
    __syncthreads();
    int e = tid, h = e >> 5;
    for (int i = 0; i < 4; i++) {
        float o = 0;
        for (int j = 0; j < 4; j++) o += sw[h][i][j] * sv[j][e];
        outb[((size_t)(seq * 4 + i)) * E_ + e] = o;
    }
}

// ---------------------------------------------------------------------------
// LayerNorm per 256-wide row. OMAP=1: write token row -> st row (transpose).
// ---------------------------------------------------------------------------
template<int OMAP>
__global__ __launch_bounds__(64) void ln_k(const float* __restrict__ in,
                                           const float* __restrict__ g,
                                           const float* __restrict__ bta,
                                           float* __restrict__ out)
{
    int row = blockIdx.x, t = threadIdx.x;
    float4 v = ((const float4*)(in + (size_t)row * E_))[t];
    float s = v.x + v.y + v.z + v.w;
#pragma unroll
    for (int o = 32; o >= 1; o >>= 1) s += __shfl_xor(s, o);
    float mean = s * (1.0f / E_);
    float dx0 = v.x - mean, dx1 = v.y - mean, dx2 = v.z - mean, dx3 = v.w - mean;
    float q = dx0 * dx0 + dx1 * dx1 + dx2 * dx2 + dx3 * dx3;
#pragma unroll
    for (int o = 32; o >= 1; o >>= 1) q += __shfl_xor(q, o);
    float inv = rsqrtf(q * (1.0f / E_) + 1e-5f);
    size_t orow;
    if (OMAP == 1) {
        int b = row >> 12, r = (row >> 2) & 1023, c = row & 3;
        orow = ((size_t)(b * CC + c)) * RR + r;
    } else orow = (size_t)row;
    int c0 = t * 4;
    float4 o;
    o.x = dx0 * inv * g[c0 + 0] + bta[c0 + 0];
    o.y = dx1 * inv * g[c0 + 1] + bta[c0 + 1];
    o.z = dx2 * inv * g[c0 + 2] + bta[c0 + 2];
    o.w = dx3 * inv * g[c0 + 3] + bta[c0 + 3];
    ((float4*)(out + orow * E_))[t] = o;
}

// ---------------------------------------------------------------------------
// Indexer projections: q32 / k32 = st_row @ {idx_q_w, idx_k_w}^T  (32 each)
// ---------------------------------------------------------------------------
__global__ __launch_bounds__(256) void idx_proj(const float* __restrict__ st,
                                                const float* __restrict__ qw,
                                                const float* __restrict__ kw,
                                                float* __restrict__ q32,
                                                float* __restrict__ k32)
{
    int row = blockIdx.x, tid = threadIdx.x;
    __shared__ float sx[E_];
    sx[tid] = st[(size_t)row * E_ + tid];
    __syncthreads();
    int d = tid >> 2, sub = tid & 3;
    const float* w = (d < 32) ? (qw + (size_t)d * E_) : (kw + (size_t)(d - 32) * E_);
    float s = 0;
    for (int k = sub; k < E_; k += 4) s += w[k] * sx[k];
    s += __shfl_xor(s, 1); s += __shfl_xor(s, 2);
    if (sub == 0) {
        if (d < 32) q32[(size_t)row * 32 + d] = s;
        else        k32[(size_t)row * 32 + (d - 32)] = s;
    }
}

// ---------------------------------------------------------------------------
// Indexer scales: 96 blocks = type(0 q-train,1 q-test,2 k-train) x bf x h
// scale = (max|.| + 1e-6)/127
// ---------------------------------------------------------------------------
__global__ __launch_bounds__(256) void idx_scales(const float* __restrict__ q32,
                                                  const float* __restrict__ k32,
                                                  float* __restrict__ scl)
{
    int id = blockIdx.x;
    int type = id / 32, bf = (id % 32) >> 2, h = id & 3;
    const float* src = (type == 2) ? k32 : q32;
    int r0 = (type == 1) ? SPLIT : 0;
    int r1 = (type == 1) ? RR : SPLIT;
    float m = 0;
    for (int r = r0 + (int)threadIdx.x; r < r1; r += 256) {
        const float* p = src + ((size_t)(bf * RR + r)) * 32 + h * 8;
        for (int dd = 0; dd < 8; dd++) m = fmaxf(m, fabsf(p[dd]));
    }
#pragma unroll
    for (int o = 32; o >= 1; o >>= 1) m = fmaxf(m, __shfl_xor(m, o));
    __shared__ float red[4];
    if ((threadIdx.x & 63) == 0) red[threadIdx.x >> 6] = m;
    __syncthreads();
    if (threadIdx.x == 0) {
        m = fmaxf(fmaxf(red[0], red[1]), fmaxf(red[2], red[3]));
        scl[id] = (m + 1e-6f) / 127.0f;
    }
}

// ---------------------------------------------------------------------------
// Quantize k (train rows only) to int8
// ---------------------------------------------------------------------------
__global__ __launch_bounds__(256) void idx_quantk(const float* __restrict__ k32,
                                                  const float* __restrict__ scl,
                                                  signed char* __restrict__ ki8)
{
    int gi = blockIdx.x * 256 + threadIdx.x;     // 0 .. 8*768*32-1
    int bf = gi / (SPLIT * 32);
    int rem = gi % (SPLIT * 32);
    int r = rem >> 5, d = rem & 31, h = d >> 3;
    float ks = scl[64 + bf * 4 + h];
    float v = k32[((size_t)(bf * RR + r)) * 32 + d];
    float qq = fminf(fmaxf(rintf(v / ks), -127.f), 127.f);
    ki8[gi] = (signed char)qq;
}

// ---------------------------------------------------------------------------
// Indexer scores + top-32. Ties -> smallest index (jax.lax.top_k semantics).
// Strategy: pack (monotone-f32, 1023-k) into u64 keys; each of 4 waves
// extracts its own top-32 of 192 candidates in registers (no barriers);
// final 128->32 merge via rank-count (keys unique -> ranks unique).
// ---------------------------------------------------------------------------
__global__ __launch_bounds__(256) void idx_score_topk(const float* __restrict__ q32,
                                                      const signed char* __restrict__ ki8,
                                                      const float* __restrict__ scl,
                                                      const float* __restrict__ ow,
                                                      int* __restrict__ idx_out)
{
    int bid = blockIdx.x, tid = threadIdx.x;
    int bf = bid >> 10, qr = bid & 1023;
    int sel = (qr < SPLIT) ? 0 : 32;
    __shared__ float qi[32];
    __shared__ float fac[4];
    __shared__ unsigned long long keys[SPLIT];
    __shared__ unsigned long long warr[4][32];
    if (tid < 32) {
        int h = tid >> 3;
        float qs = scl[sel + bf * 4 + h];
        float v = q32[((size_t)bid) * 32 + tid];
        qi[tid] = fminf(fmaxf(rintf(v / qs), -127.f), 127.f);
    }
    if (tid < 4) {
        float qs = scl[sel + bf * 4 + tid];
        float ks = scl[64 + bf * 4 + tid];
        fac[tid] = __fmul_rn(qs, ks);
    }
    __syncthreads();
    for (int k = tid; k < SPLIT; k += 256) {
        const signed char* kp = ki8 + ((size_t)(bf * SPLIT + k)) * 32;
        float r = 0;
#pragma unroll
        for (int h = 0; h < 4; h++) {
            float dot = 0;
#pragma unroll
            for (int dd = 0; dd < 8; dd++)
                dot = __fadd_rn(dot, __fmul_rn(qi[h * 8 + dd], (float)kp[h * 8 + dd]));
            float sc = fmaxf(__fmul_rn(dot, fac[h]), 0.f);
            r = __fadd_rn(r, __fmul_rn(sc, ow[h]));
        }
        unsigned int bitsv = __float_as_uint(r);
        unsigned int mono = (bitsv & 0x80000000u) ? ~bitsv : (bitsv | 0x80000000u);
        if (mono == 0x7FFFFFFFu) mono = 0x80000000u;   // canonicalize -0 == +0
        keys[k] = ((unsigned long long)mono << 32) | (unsigned int)(1023 - k);
    }
    __syncthreads();
    // per-wave top-32 over 192 candidates, in registers, barrier-free
    {
        int w = tid >> 6, lane = tid & 63;
        unsigned long long a0 = keys[w * 192 + lane];
        unsigned long long a1 = keys[w * 192 + 64 + lane];
        unsigned long long a2 = keys[w * 192 + 128 + lane];
        for (int it = 0; it < TOPK_; it++) {
            unsigned long long m = a0 > a1 ? a0 : a1;
            if (a2 > m) m = a2;
#pragma unroll
            for (int o = 1; o < 64; o <<= 1) {
                unsigned long long other = __shfl_xor(m, o);
                if (other > m) m = other;
            }
            if (lane == 0) warr[w][it] = m;
            if (a0 == m) a0 = 0ull;
            else if (a1 == m) a1 = 0ull;
            else if (a2 == m) a2 = 0ull;
        }
    }
    __syncthreads();
    // merge 4x32 -> global top-32 via rank-count (broadcast LDS reads)
    if (tid < 128) {
        const unsigned long long mine = (&warr[0][0])[tid];
        const unsigned long long* wf = &warr[0][0];
        int r = 0;
        for (int j = 0; j < 128; j++) r += (wf[j] > mine) ? 1 : 0;
        if (r < TOPK_)
            idx_out[(size_t)bid * TOPK_ + r] = 1023 - (int)(unsigned int)(mine & 0xFFFFFFFFull);
    }
}

// ---------------------------------------------------------------------------
// MLA absorption part 1: G[q][h][l] = sum_d qbuf[q][h*32+d] * up_w[h*32+d][l]
// grid (128 qtiles, 8 heads)
// ---------------------------------------------------------------------------
__global__ __launch_bounds__(256) void mla_g(const float* __restrict__ qb,
                                             const float* __restrict__ uw,
                                             float* __restrict__ G)
{
    int qt = blockIdx.x, h = blockIdx.y, tid = threadIdx.x;
    __shared__ float Qs[64][33];
    __shared__ float Us[32][132];
    {
        int r = tid >> 2, c0 = (tid & 3) * 8;
        const float* srcp = qb + ((size_t)(qt * 64 + r)) * E_ + h * DH + c0;
        float4 a = ((const float4*)srcp)[0];
        float4 b = ((const float4*)srcp)[1];
        Qs[r][c0 + 0] = a.x; Qs[r][c0 + 1] = a.y; Qs[r][c0 + 2] = a.z; Qs[r][c0 + 3] = a.w;
        Qs[r][c0 + 4] = b.x; Qs[r][c0 + 5] = b.y; Qs[r][c0 + 6] = b.z; Qs[r][c0 + 7] = b.w;
    }
    {
        int d = tid >> 3, l0 = (tid & 7) * 16;
        const float* srcp = uw + (size_t)(h * DH + d) * LATD + l0;
#pragma unroll
        for (int ii = 0; ii < 4; ii++) {
            float4 v = ((const float4*)srcp)[ii];
            *(float4*)&Us[d][l0 + ii * 4] = v;
        }
    }
    __syncthreads();
    int rg = tid >> 5, l = (tid & 31) * 4;
    float acc[8][4];
#pragma unroll
    for (int i = 0; i < 8; i++)
#pragma unroll
        for (int j = 0; j < 4; j++) acc[i][j] = 0.f;
    for (int d = 0; d < DH; d++) {
        float4 u = *(const float4*)&Us[d][l];
#pragma unroll
        for (int i = 0; i < 8; i++) {
            float qv = Qs[rg * 8 + i][d];
            acc[i][0] += qv * u.x; acc[i][1] += qv * u.y;
            acc[i][2] += qv * u.z; acc[i][3] += qv * u.w;
        }
    }
#pragma unroll
    for (int i = 0; i < 8; i++) {
        float4 o = {acc[i][0], acc[i][1], acc[i][2], acc[i][3]};
        *(float4*)(G + ((size_t)(qt * 64 + rg * 8 + i)) * 1024 + h * 128 + l) = o;
    }
}

// ---------------------------------------------------------------------------
// Fused sparse MLA attention per (bf, q): scores from G . c_sel, softmax,
// M[h][l] = sum_j w[j][h] * c_sel[j][l]
// ---------------------------------------------------------------------------
__global__ __launch_bounds__(256) void mla_attn(const float* __restrict__ G,
                                                const float* __restrict__ cb,
                                                const int* __restrict__ idxb,
                                                float* __restrict__ Mo)
{
    int bid = blockIdx.x, tid = threadIdx.x;
    int bf = bid >> 10;
    __shared__ float cs[32][132];
    __shared__ float gs[8][132];
    __shared__ float swt[32][8];
    __shared__ int sidx[32];
    if (tid < 32) sidx[tid] = idxb[(size_t)bid * 32 + tid];
    {
        int flat = tid * 4, h = flat >> 7, l = flat & 127;
        float4 gv = *(const float4*)(G + (size_t)bid * 1024 + flat);
        *(float4*)&gs[h][l] = gv;
    }
    __syncthreads();
    {
        int j = tid >> 3, l0 = (tid & 7) * 16;
        const float* srcp = cb + ((size_t)(bf * SPLIT + sidx[j])) * LATD + l0;
#pragma unroll
        for (int ii = 0; ii < 4; ii++) {
            float4 vv = ((const float4*)srcp)[ii];
            *(float4*)&cs[j][l0 + ii * 4] = vv;
        }
    }
    __syncthreads();
    {
        int j = tid >> 3, h = tid & 7;
        float s = 0;
#pragma unroll
        for (int lb = 0; lb < 32; lb++) {
            float4 c4 = *(const float4*)&cs[j][lb * 4];
            float4 g4 = *(const float4*)&gs[h][lb * 4];
            s += c4.x * g4.x + c4.y * g4.y + c4.z * g4.z + c4.w * g4.w;
        }
        swt[j][h] = s * 0.17677669529663688f;
    }
    __syncthreads();
    if (tid < 8) {
        float m = swt[0][tid];
        for (int j = 1; j < 32; j++) m = fmaxf(m, swt[j][tid]);
        float sum = 0;
        for (int j = 0; j < 32; j++) { float e = expf(swt[j][tid] - m); swt[j][tid] = e; sum += e; }
        float inv = 1.0f / sum;
        for (int j = 0; j < 32; j++) swt[j][tid] *= inv;
    }
    __syncthreads();
    {
        int flat = tid * 4, h = flat >> 7, l = flat & 127;
        float4 acc = {0, 0, 0, 0};
        for (int j = 0; j < 32; j++) {
            float w = swt[j][h];
            float4 c4 = *(const float4*)&cs[j][l];
            acc.x += w * c4.x; acc.y += w * c4.y; acc.z += w * c4.z; acc.w += w * c4.w;
        }
        *(float4*)(Mo + (size_t)bid * 1024 + flat) = acc;
    }
}

// ---------------------------------------------------------------------------
// MLA absorption part 2: out[q][h*32+d] = sum_l M[q][h][l] * up_w[256+h*32+d][l]
// ---------------------------------------------------------------------------
__global__ __launch_bounds__(256) void mla_out(const float* __restrict__ Mo,
                                               const float* __restrict__ uw,
                                               float* __restrict__ ob)
{
    int qt = blockIdx.x, h = blockIdx.y, tid = threadIdx.x;
    __shared__ float Ms[64][132];
    __shared__ float Us[32][129];
    {
        int r = tid >> 2, l0 = (tid & 3) * 32;
        const float* srcp = Mo + ((size_t)(qt * 64 + r)) * 1024 + h * 128 + l0;
#pragma unroll
        for (int ii = 0; ii < 8; ii++) {
            float4 v = ((const float4*)srcp)[ii];
            *(float4*)&Ms[r][l0 + ii * 4] = v;
        }
    }
    {
        int d = tid >> 3, l0 = (tid & 7) * 16;
        const float* srcp = uw + (size_t)(256 + h * DH + d) * LATD + l0;
#pragma unroll
        for (int ii = 0; ii < 4; ii++) {
            float4 v = ((const float4*)srcp)[ii];
            Us[d][l0 + ii * 4 + 0] = v.x; Us[d][l0 + ii * 4 + 1] = v.y;
            Us[d][l0 + ii * 4 + 2] = v.z; Us[d][l0 + ii * 4 + 3] = v.w;
        }
    }
    __syncthreads();
    int d = tid & 31, rg = tid >> 5;
    float acc[8] = {0, 0, 0, 0, 0, 0, 0, 0};
    for (int l = 0; l < 128; l++) {
        float u = Us[d][l];
#pragma unroll
        for (int i = 0; i < 8; i++) acc[i] += Ms[rg * 8 + i][l] * u;
    }
#pragma unroll
    for (int i = 0; i < 8; i++)
        ob[((size_t)(qt * 64 + rg * 8 + i)) * E_ + h * DH + d] = acc[i];
}

// ---------------------------------------------------------------------------
extern "C" void kernel_launch(void* const* d_in, const int* in_sizes, int n_in,
                              void* d_out, int out_size, void* d_ws, size_t ws_size,
                              hipStream_t stream)
{
    (void)in_sizes; (void)n_in; (void)out_size; (void)ws_size;
    const float* src      = (const float*)d_in[0];
    // d_in[1] = train_test_split_index (always 768 in this dataset)
    const float* fa_in_w  = (const float*)d_in[2];
    const float* fa_in_b  = (const float*)d_in[3];
    const float* fa_out_w = (const float*)d_in[4];
    const float* fa_out_b = (const float*)d_in[5];
    const float* n1g = (const float*)d_in[6];
    const float* n1b = (const float*)d_in[7];
    const float* iqw = (const float*)d_in[8];
    const float* ikw = (const float*)d_in[9];
    const float* iow = (const float*)d_in[10];
    const float* mqw = (const float*)d_in[11];
    const float* mdw = (const float*)d_in[12];
    const float* muw = (const float*)d_in[13];
    const float* mow = (const float*)d_in[14];
    const float* n2g = (const float*)d_in[15];
    const float* n2b = (const float*)d_in[16];
    const float* l1w = (const float*)d_in[17];
    const float* l1b = (const float*)d_in[18];
    const float* l2w = (const float*)d_in[19];
    const float* l2b = (const float*)d_in[20];
    const float* n3g = (const float*)d_in[21];
    const float* n3b = (const float*)d_in[22];

    float* ws = (float*)d_ws;
    size_t off = 0;
    float* ws0  = ws + off; off += (size_t)NT * 1024;   // qkv -> G -> h1
    float* ws1  = ws + off; off += (size_t)NT * 1024;   // M
    float* abuf = ws + off; off += (size_t)NT * E_;     // attn-out -> mla_q -> mla-attn-out
    float* stb  = ws + off; off += (size_t)NT * E_;     // st (post-LN1, transposed layout)
    float* tbuf = ws + off; off += (size_t)NT * E_;     // pre-LN1 -> pre-LN2 -> pre-LN3
    float* x2   = ws + off; off += (size_t)NT * E_;     // LN2 out (MLP residual)
    float* q32  = ws + off; off += (size_t)NT * 32;
    float* k32  = ws + off; off += (size_t)NT * 32;
    float* scl  = ws + off; off += 128;
    float* cb   = ws + off; off += (size_t)BF * SPLIT * LATD;
    int*   idxb = (int*)(ws + off); off += (size_t)NT * 32;
    signed char* ki8 = (signed char*)(ws + off); off += (size_t)NT * 32 / 4;

    dim3 blk(256);
    // 1. qkv = src @ fa_in_w^T + b
    gemm_abt<1,0,0,0,0><<<dim3(12,128), blk, 0, stream>>>(src, fa_in_w, fa_in_b, nullptr, ws0, NT, 768, 256);
    // 2. feature attention (S=4)
    fa_attn<<<2048, blk, 0, stream>>>(ws0, abuf);
    // 3. out-proj + bias + residual(src)
    gemm_abt<1,0,1,0,0><<<dim3(4,128), blk, 0, stream>>>(abuf, fa_out_w, fa_out_b, src, tbuf, NT, 256, 256);
    // 4. LN1, write transposed (token -> st row)
    ln_k<1><<<NT, dim3(64), 0, stream>>>(tbuf, n1g, n1b, stb);
    // 5. indexer projections
    idx_proj<<<NT, blk, 0, stream>>>(stb, iqw, ikw, q32, k32);
    // 6. scales
    idx_scales<<<96, blk, 0, stream>>>(q32, k32, scl);
    // 7. quantize k
    idx_quantk<<<(BF*SPLIT*32)/256, blk, 0, stream>>>(k32, scl, ki8);
    // 8. scores + top-32
    idx_score_topk<<<NT, blk, 0, stream>>>(q32, ki8, scl, iow, idxb);
    // 9. c = x_tr @ down_w^T   (train rows only)
    gemm_abt<0,0,0,1,0><<<dim3(2,96), blk, 0, stream>>>(stb, mdw, nullptr, nullptr, cb, BF*SPLIT, LATD, 256);
    // 10. mla q projection
    gemm_abt<0,0,0,0,0><<<dim3(4,128), blk, 0, stream>>>(stb, mqw, nullptr, nullptr, abuf, NT, 256, 256);
    // 11. G = per-head up_w(K-half)^T @ q
    mla_g<<<dim3(128,8), blk, 0, stream>>>(abuf, muw, ws0);
    // 12. fused sparse attention -> M
    mla_attn<<<NT, blk, 0, stream>>>(ws0, cb, idxb, ws1);
    // 13. out = per-head up_w(V-half) @ M
    mla_out<<<dim3(128,8), blk, 0, stream>>>(ws1, muw, abuf);
    // 14. mla out-proj + residual(st), write transposed back to BRCE
    gemm_abt<0,0,1,0,1><<<dim3(4,128), blk, 0, stream>>>(abuf, mow, nullptr, stb, tbuf, NT, 256, 256);
    // 15. LN2
    ln_k<0><<<NT, dim3(64), 0, stream>>>(tbuf, n2g, n2b, x2);
    // 16. MLP1 + GELU
    gemm_abt<1,1,0,0,0><<<dim3(16,128), blk, 0, stream>>>(x2, l1w, l1b, nullptr, ws0, NT, MLPD, 256);
    // 17. MLP2 + bias + residual(x2)
    gemm_abt<1,0,1,0,0><<<dim3(4,128), blk, 0, stream>>>(ws0, l2w, l2b, x2, tbuf, NT, 256, MLPD);
    // 18. LN3 -> output
    ln_k<0><<<NT, dim3(64), 0, stream>>>(tbuf, n3g, n3b, (float*)d_out);
}

// Round 3
// 528.840 us; speedup vs baseline: 1.4218x; 1.3127x over previous
//
#include <hip/hip_runtime.h>
#include <hip/hip_bf16.h>
#include <cmath>

#define E_ 256
#define H_ 8
#define DH 32
#define MLPD 1024
#define LATD 128
#define TOPK_ 32
#define BB 2
#define RR 1024
#define CC 4
#define NT 8192      // B*R*C tokens
#define BF 8         // B*C
#define SPLIT 768

using bf16x8 = __attribute__((ext_vector_type(8))) short;
using f32x4v = __attribute__((ext_vector_type(4))) float;

__device__ __forceinline__ unsigned short f2b(float x) {
    __hip_bfloat16 h = __float2bfloat16(x);
    return *reinterpret_cast<unsigned short*>(&h);
}

// ---------------------------------------------------------------------------
// Fused f32 -> bf16 converter for weights + src (8 segments)
// ---------------------------------------------------------------------------
struct ConvArgs {
    const float* s[8];
    unsigned short* d[8];
    int cum[8];   // cumulative quad counts (exclusive prefix ends)
};
__global__ __launch_bounds__(256) void convert_f2b(ConvArgs a, int totq)
{
    int q = blockIdx.x * 256 + threadIdx.x;
    if (q >= totq) return;
    int seg = 0;
    while (q >= a.cum[seg]) seg++;
    int lq = q - (seg ? a.cum[seg - 1] : 0);
    float4 v = ((const float4*)a.s[seg])[lq];
    ushort4 o;
    o.x = f2b(v.x); o.y = f2b(v.y); o.z = f2b(v.z); o.w = f2b(v.w);
    ((ushort4*)a.d[seg])[lq] = o;
}

// ---------------------------------------------------------------------------
// bf16 MFMA GEMM: C[M][N] = A(MxK bf16) @ W(NxK bf16)^T (+bias)(+gelu)(+res f32)
// 128x128 tile, 4 waves (2x2), each wave 64x64 via 4x4 frags of 16x16x32.
// AMAP: A-row gather (train rows). OMAP: st-row -> BRCE token row scatter.
// OUTBF: write bf16 (Ch) instead of f32 (Cf).
// ---------------------------------------------------------------------------
template<int BIAS, int GELU, int RES, int AMAP, int OMAP, int OUTBF>
__global__ __launch_bounds__(256) void gemm_mfma(
    const unsigned short* __restrict__ A, const unsigned short* __restrict__ W,
    const float* __restrict__ bias, const float* __restrict__ res,
    float* __restrict__ Cf, unsigned short* __restrict__ Ch,
    int M, int N, int K)
{
    __shared__ __align__(16) unsigned short As[128 * 40];
    __shared__ __align__(16) unsigned short Bs[128 * 40];
    const int tid = threadIdx.x;
    const int lane = tid & 63, wave = tid >> 6;
    const int wr = wave >> 1, wc = wave & 1;
    const int m0 = blockIdx.y * 128, n0 = blockIdx.x * 128;

    // staging: thread -> row ra (0..127), k-chunk kq (0 or 16)
    const int ra = tid >> 1, kq = (tid & 1) * 16;
    int am = m0 + ra;
    size_t arow = AMAP ? ((size_t)(am / SPLIT) * RR + (am % SPLIT)) : (size_t)am;
    const unsigned short* Ap = A + arow * (size_t)K + kq;
    const unsigned short* Bp = W + (size_t)(n0 + ra) * K + kq;

    f32x4v acc[4][4];
#pragma unroll
    for (int i = 0; i < 4; i++)
#pragma unroll
        for (int j = 0; j < 4; j++) acc[i][j] = (f32x4v){0.f, 0.f, 0.f, 0.f};

    const int kof = (lane >> 4) * 8;
    const int arow_lds[4] = {
        (wr * 64 + 0 * 16 + (lane & 15)) * 40 + kof,
        (wr * 64 + 1 * 16 + (lane & 15)) * 40 + kof,
        (wr * 64 + 2 * 16 + (lane & 15)) * 40 + kof,
        (wr * 64 + 3 * 16 + (lane & 15)) * 40 + kof };
    const int brow_lds[4] = {
        (wc * 64 + 0 * 16 + (lane & 15)) * 40 + kof,
        (wc * 64 + 1 * 16 + (lane & 15)) * 40 + kof,
        (wc * 64 + 2 * 16 + (lane & 15)) * 40 + kof,
        (wc * 64 + 3 * 16 + (lane & 15)) * 40 + kof };

    for (int k0 = 0; k0 < K; k0 += 32) {
        int4 va0 = *(const int4*)(Ap + k0);
        int4 va1 = *(const int4*)(Ap + k0 + 8);
        int4 vb0 = *(const int4*)(Bp + k0);
        int4 vb1 = *(const int4*)(Bp + k0 + 8);
        __syncthreads();
        *(int4*)&As[ra * 40 + kq] = va0;
        *(int4*)&As[ra * 40 + kq + 8] = va1;
        *(int4*)&Bs[ra * 40 + kq] = vb0;
        *(int4*)&Bs[ra * 40 + kq + 8] = vb1;
        __syncthreads();
        bf16x8 af[4], bf[4];
#pragma unroll
        for (int f = 0; f < 4; f++) {
            af[f] = *(const bf16x8*)&As[arow_lds[f]];
            bf[f] = *(const bf16x8*)&Bs[brow_lds[f]];
        }
#pragma unroll
        for (int fm = 0; fm < 4; fm++)
#pragma unroll
            for (int fn = 0; fn < 4; fn++)
                acc[fm][fn] = __builtin_amdgcn_mfma_f32_16x16x32_bf16(
                    af[fm], bf[fn], acc[fm][fn], 0, 0, 0);
    }

#pragma unroll
    for (int fm = 0; fm < 4; fm++) {
#pragma unroll
        for (int r = 0; r < 4; r++) {
            int row = m0 + wr * 64 + fm * 16 + ((lane >> 4) << 2) + r;
            size_t orow;
            if (OMAP) {
                int bc = row >> 10, rr = row & 1023;
                int b = bc >> 2, c = bc & 3;
                orow = ((size_t)(b * RR + rr)) * CC + c;
            } else orow = (size_t)row;
#pragma unroll
            for (int fn = 0; fn < 4; fn++) {
                int col = n0 + wc * 64 + fn * 16 + (lane & 15);
                float v = acc[fm][fn][r];
                if (BIAS) v += bias[col];
                if (GELU) v = 0.5f * v * (1.0f + erff(v * 0.70710678118654752f));
                if (RES)  v += res[(size_t)row * N + col];
                if (OUTBF) Ch[orow * (size_t)N + col] = f2b(v);
                else       Cf[orow * (size_t)N + col] = v;
            }
        }
    }
}

// ---------------------------------------------------------------------------
// Feature attention: seq len 4, per (b,r) block. Reads qkv f32, writes bf16.
// ---------------------------------------------------------------------------
__global__ __launch_bounds__(256) void fa_attn(const float* __restrict__ qkv,
                                               unsigned short* __restrict__ outb)
{
    int seq = blockIdx.x, tid = threadIdx.x;
    __shared__ float sq[4][E_], sk[4][E_], sv[4][E_];
    __shared__ float ss[H_][4][4];
    __shared__ float sw[H_][4][4];
    for (int i = 0; i < 4; i++) {
        const float* srcp = qkv + ((size_t)(seq * 4 + i)) * 768;
        for (int idx = tid; idx < 768; idx += 256) {
            float v = srcp[idx];
            if (idx < 256) sq[i][idx] = v;
            else if (idx < 512) sk[i][idx - 256] = v;
            else sv[i][idx - 512] = v;
        }
    }
    __syncthreads();
    if (tid < 128) {
        int h = tid >> 4, i = (tid >> 2) & 3, j = tid & 3;
        float s = 0;
        for (int d = 0; d < DH; d++) s += sq[i][h * DH + d] * sk[j][h * DH + d];
        ss[h][i][j] = s * 0.17677669529663688f;   // 1/sqrt(32)
    }
    __syncthreads();
    if (tid < 32) {
        int h = tid >> 2, i = tid & 3;
        float m = ss[h][i][0];
        for (int j = 1; j < 4; j++) m = fmaxf(m, ss[h][i][j]);
        float e[4], sum = 0;
        for (int j = 0; j < 4; j++) { e[j] = expf(ss[h][i][j] - m); sum += e[j]; }
        float inv = 1.0f / sum;
        for (int j = 0; j < 4; j++) sw[h][i][j] = e[j] * inv;
    }
    __syncthreads();
    int e = tid, h = e >> 5;
    for (int i = 0; i < 4; i++) {
        float o = 0;
        for (int j = 0; j < 4; j++) o += sw[h][i][j] * sv[j][e];
        outb[((size_t)(seq * 4 + i)) * E_ + e] = f2b(o);
    }
}

// ---------------------------------------------------------------------------
// LayerNorm per 256-wide row. OMAP=1: token row -> st row (transpose).
// WB=1: also write bf16 copy.
// ---------------------------------------------------------------------------
template<int OMAP, int WB>
__global__ __launch_bounds__(64) void ln_k(const float* __restrict__ in,
                                           const float* __restrict__ g,
                                           const float* __restrict__ bta,
                                           float* __restrict__ out,
                                           unsigned short* __restrict__ outh)
{
    int row = blockIdx.x, t = threadIdx.x;
    float4 v = ((const float4*)(in + (size_t)row * E_))[t];
    float s = v.x + v.y + v.z + v.w;
#pragma unroll
    for (int o = 32; o >= 1; o >>= 1) s += __shfl_xor(s, o);
    float mean = s * (1.0f / E_);
    float dx0 = v.x - mean, dx1 = v.y - mean, dx2 = v.z - mean, dx3 = v.w - mean;
    float q = dx0 * dx0 + dx1 * dx1 + dx2 * dx2 + dx3 * dx3;
#pragma unroll
    for (int o = 32; o >= 1; o >>= 1) q += __shfl_xor(q, o);
    float inv = rsqrtf(q * (1.0f / E_) + 1e-5f);
    size_t orow;
    if (OMAP == 1) {
        int b = row >> 12, r = (row >> 2) & 1023, c = row & 3;
        orow = ((size_t)(b * CC + c)) * RR + r;
    } else orow = (size_t)row;
    int c0 = t * 4;
    float4 o;
    o.x = dx0 * inv * g[c0 + 0] + bta[c0 + 0];
    o.y = dx1 * inv * g[c0 + 1] + bta[c0 + 1];
    o.z = dx2 * inv * g[c0 + 2] + bta[c0 + 2];
    o.w = dx3 * inv * g[c0 + 3] + bta[c0 + 3];
    ((float4*)(out + orow * E_))[t] = o;
    if (WB) {
        ushort4 oh; oh.x = f2b(o.x); oh.y = f2b(o.y); oh.z = f2b(o.z); oh.w = f2b(o.w);
        ((ushort4*)(outh + orow * E_))[t] = oh;
    }
}

// ---------------------------------------------------------------------------
// Indexer projections: q32 / k32 = st_row @ {idx_q_w, idx_k_w}^T  (32 each)
// ---------------------------------------------------------------------------
__global__ __launch_bounds__(256) void idx_proj(const float* __restrict__ st,
                                                const float* __restrict__ qw,
                                                const float* __restrict__ kw,
                                                float* __restrict__ q32,
                                                float* __restrict__ k32)
{
    int row = blockIdx.x, tid = threadIdx.x;
    __shared__ float sx[E_];
    sx[tid] = st[(size_t)row * E_ + tid];
    __syncthreads();
    int d = tid >> 2, sub = tid & 3;
    const float* w = (d < 32) ? (qw + (size_t)d * E_) : (kw + (size_t)(d - 32) * E_);
    float s = 0;
    for (int k = sub; k < E_; k += 4) s += w[k] * sx[k];
    s += __shfl_xor(s, 1); s += __shfl_xor(s, 2);
    if (sub == 0) {
        if (d < 32) q32[(size_t)row * 32 + d] = s;
        else        k32[(size_t)row * 32 + (d - 32)] = s;
    }
}

// ---------------------------------------------------------------------------
// Indexer scales: 96 blocks = type(0 q-train,1 q-test,2 k-train) x bf x h
// ---------------------------------------------------------------------------
__global__ __launch_bounds__(256) void idx_scales(const float* __restrict__ q32,
                                                  const float* __restrict__ k32,
                                                  float* __restrict__ scl)
{
    int id = blockIdx.x;
    int type = id / 32, bf = (id % 32) >> 2, h = id & 3;
    const float* src = (type == 2) ? k32 : q32;
    int r0 = (type == 1) ? SPLIT : 0;
    int r1 = (type == 1) ? RR : SPLIT;
    float m = 0;
    for (int r = r0 + (int)threadIdx.x; r < r1; r += 256) {
        const float* p = src + ((size_t)(bf * RR + r)) * 32 + h * 8;
        for (int dd = 0; dd < 8; dd++) m = fmaxf(m, fabsf(p[dd]));
    }
#pragma unroll
    for (int o = 32; o >= 1; o >>= 1) m = fmaxf(m, __shfl_xor(m, o));
    __shared__ float red[4];
    if ((threadIdx.x & 63) == 0) red[threadIdx.x >> 6] = m;
    __syncthreads();
    if (threadIdx.x == 0) {
        m = fmaxf(fmaxf(red[0], red[1]), fmaxf(red[2], red[3]));
        scl[id] = (m + 1e-6f) / 127.0f;
    }
}

// ---------------------------------------------------------------------------
// Quantize k (train rows only) to int8
// ---------------------------------------------------------------------------
__global__ __launch_bounds__(256) void idx_quantk(const float* __restrict__ k32,
                                                  const float* __restrict__ scl,
                                                  signed char* __restrict__ ki8)
{
    int gi = blockIdx.x * 256 + threadIdx.x;     // 0 .. 8*768*32-1
    int bf = gi / (SPLIT * 32);
    int rem = gi % (SPLIT * 32);
    int r = rem >> 5, d = rem & 31, h = d >> 3;
    float ks = scl[64 + bf * 4 + h];
    float v = k32[((size_t)(bf * RR + r)) * 32 + d];
    float qq = fminf(fmaxf(rintf(v / ks), -127.f), 127.f);
    ki8[gi] = (signed char)qq;
}

// ---------------------------------------------------------------------------
// Indexer scores + top-32. Ties -> smallest index (jax.lax.top_k semantics).
// Score phase: vectorized int4 loads of k-bytes, bfe/cvt/fma (exact integer
// arithmetic in f32 -> bit-identical to mul_rn/add_rn chain).
// Selection: per-wave reg top-32 butterfly + rank-count merge.
// ---------------------------------------------------------------------------
__global__ __launch_bounds__(256) void idx_score_topk(const float* __restrict__ q32,
                                                      const signed char* __restrict__ ki8,
                                                      const float* __restrict__ scl,
                                                      const float* __restrict__ ow,
                                                      int* __restrict__ idx_out)
{
    int bid = blockIdx.x, tid = threadIdx.x;
    int bf = bid >> 10, qr = bid & 1023;
    int sel = (qr < SPLIT) ? 0 : 32;
    __shared__ float qi[32];
    __shared__ float fac[4];
    __shared__ unsigned long long keys[SPLIT];
    __shared__ unsigned long long warr[4][32];
    if (tid < 32) {
        int h = tid >> 3;
        float qs = scl[sel + bf * 4 + h];
        float v = q32[((size_t)bid) * 32 + tid];
        qi[tid] = fminf(fmaxf(rintf(v / qs), -127.f), 127.f);
    }
    if (tid < 4) {
        float qs = scl[sel + bf * 4 + tid];
        float ks = scl[64 + bf * 4 + tid];
        fac[tid] = __fmul_rn(qs, ks);
    }
    __syncthreads();
    float ow0 = ow[0], ow1 = ow[1], ow2 = ow[2], ow3 = ow[3];
    for (int k = tid; k < SPLIT; k += 256) {
        const int4* kp4 = (const int4*)(ki8 + ((size_t)(bf * SPLIT + k)) * 32);
        int4 w0 = kp4[0], w1 = kp4[1];
        int wd[8] = {w0.x, w0.y, w0.z, w0.w, w1.x, w1.y, w1.z, w1.w};
        float owv[4] = {ow0, ow1, ow2, ow3};
        float r = 0;
#pragma unroll
        for (int h = 0; h < 4; h++) {
            float dot = 0.f;
#pragma unroll
            for (int b = 0; b < 2; b++) {
                unsigned int w = (unsigned int)wd[h * 2 + b];
#pragma unroll
                for (int by = 0; by < 4; by++) {
                    float kv = (float)((signed char)(w >> (8 * by)));
                    dot = fmaf(qi[h * 8 + b * 4 + by], kv, dot);
                }
            }
            float sc = fmaxf(__fmul_rn(dot, fac[h]), 0.f);
            r = __fadd_rn(r, __fmul_rn(sc, owv[h]));
        }
        unsigned int bitsv = __float_as_uint(r);
        unsigned int mono = (bitsv & 0x80000000u) ? ~bitsv : (bitsv | 0x80000000u);
        if (mono == 0x7FFFFFFFu) mono = 0x80000000u;   // canonicalize -0 == +0
        keys[k] = ((unsigned long long)mono << 32) | (unsigned int)(1023 - k);
    }
    __syncthreads();
    // per-wave top-32 over 192 candidates, in registers, barrier-free
    {
        int w = tid >> 6, lane = tid & 63;
        unsigned long long a0 = keys[w * 192 + lane];
        unsigned long long a1 = keys[w * 192 + 64 + lane];
        unsigned long long a2 = keys[w * 192 + 128 + lane];
        for (int it = 0; it < TOPK_; it++) {
            unsigned long long m = a0 > a1 ? a0 : a1;
            if (a2 > m) m = a2;
#pragma unroll
            for (int o = 1; o < 64; o <<= 1) {
                unsigned long long other = __shfl_xor(m, o);
                if (other > m) m = other;
            }
            if (lane == 0) warr[w][it] = m;
            if (a0 == m) a0 = 0ull;
            else if (a1 == m) a1 = 0ull;
            else if (a2 == m) a2 = 0ull;
        }
    }
    __syncthreads();
    // merge 4x32 -> global top-32 via rank-count
    if (tid < 128) {
        const unsigned long long mine = (&warr[0][0])[tid];
        const unsigned long long* wf = &warr[0][0];
        int r = 0;
        for (int j = 0; j < 128; j++) r += (wf[j] > mine) ? 1 : 0;
        if (r < TOPK_)
            idx_out[(size_t)bid * TOPK_ + r] = 1023 - (int)(unsigned int)(mine & 0xFFFFFFFFull);
    }
}

// ---------------------------------------------------------------------------
// MLA absorption part 1: G[q][h][l] = sum_d qb[q][h*32+d] * up_w[h*32+d][l]
// ---------------------------------------------------------------------------
__global__ __launch_bounds__(256) void mla_g(const float* __restrict__ qb,
                                             const float* __restrict__ uw,
                                             float* __restrict__ G)
{
    int qt = blockIdx.x, h = blockIdx.y, tid = threadIdx.x;
    __shared__ float Qs[64][33];
    __shared__ float Us[32][132];
    {
        int r = tid >> 2, c0 = (tid & 3) * 8;
        const float* srcp = qb + ((size_t)(qt * 64 + r)) * E_ + h * DH + c0;
        float4 a = ((const float4*)srcp)[0];
        float4 b = ((const float4*)srcp)[1];
        Qs[r][c0 + 0] = a.x; Qs[r][c0 + 1] = a.y; Qs[r][c0 + 2] = a.z; Qs[r][c0 + 3] = a.w;
        Qs[r][c0 + 4] = b.x; Qs[r][c0 + 5] = b.y; Qs[r][c0 + 6] = b.z; Qs[r][c0 + 7] = b.w;
    }
    {
        int d = tid >> 3, l0 = (tid & 7) * 16;
        const float* srcp = uw + (size_t)(h * DH + d) * LATD + l0;
#pragma unroll
        for (int ii = 0; ii < 4; ii++) {
            float4 v = ((const float4*)srcp)[ii];
            *(float4*)&Us[d][l0 + ii * 4] = v;
        }
    }
    __syncthreads();
    int rg = tid >> 5, l = (tid & 31) * 4;
    float acc[8][4];
#pragma unroll
    for (int i = 0; i < 8; i++)
#pragma unroll
        for (int j = 0; j < 4; j++) acc[i][j] = 0.f;
    for (int d = 0; d < DH; d++) {
        float4 u = *(const float4*)&Us[d][l];
#pragma unroll
        for (int i = 0; i < 8; i++) {
            float qv = Qs[rg * 8 + i][d];
            acc[i][0] += qv * u.x; acc[i][1] += qv * u.y;
            acc[i][2] += qv * u.z; acc[i][3] += qv * u.w;
        }
    }
#pragma unroll
    for (int i = 0; i < 8; i++) {
        float4 o = {acc[i][0], acc[i][1], acc[i][2], acc[i][3]};
        *(float4*)(G + ((size_t)(qt * 64 + rg * 8 + i)) * 1024 + h * 128 + l) = o;
    }
}

// ---------------------------------------------------------------------------
// Fused sparse MLA attention per (bf, q)
// ---------------------------------------------------------------------------
__global__ __launch_bounds__(256) void mla_attn(const float* __restrict__ G,
                                                const float* __restrict__ cb,
                                                const int* __restrict__ idxb,
                                                float* __restrict__ Mo)
{
    int bid = blockIdx.x, tid = threadIdx.x;
    int bf = bid >> 10;
    __shared__ float cs[32][132];
    __shared__ float gs[8][132];
    __shared__ float swt[32][8];
    __shared__ int sidx[32];
    if (tid < 32) sidx[tid] = idxb[(size_t)bid * 32 + tid];
    {
        int flat = tid * 4, h = flat >> 7, l = flat & 127;
        float4 gv = *(const float4*)(G + (size_t)bid * 1024 + flat);
        *(float4*)&gs[h][l] = gv;
    }
    __syncthreads();
    {
        int j = tid >> 3, l0 = (tid & 7) * 16;
        const float* srcp = cb + ((size_t)(bf * SPLIT + sidx[j])) * LATD + l0;
#pragma unroll
        for (int ii = 0; ii < 4; ii++) {
            float4 vv = ((const float4*)srcp)[ii];
            *(float4*)&cs[j][l0 + ii * 4] = vv;
        }
    }
    __syncthreads();
    {
        int j = tid >> 3, h = tid & 7;
        float s = 0;
#pragma unroll
        for (int lb = 0; lb < 32; lb++) {
            float4 c4 = *(const float4*)&cs[j][lb * 4];
            float4 g4 = *(const float4*)&gs[h][lb * 4];
            s += c4.x * g4.x + c4.y * g4.y + c4.z * g4.z + c4.w * g4.w;
        }
        swt[j][h] = s * 0.17677669529663688f;
    }
    __syncthreads();
    if (tid < 8) {
        float m = swt[0][tid];
        for (int j = 1; j < 32; j++) m = fmaxf(m, swt[j][tid]);
        float sum = 0;
        for (int j = 0; j < 32; j++) { float e = expf(swt[j][tid] - m); swt[j][tid] = e; sum += e; }
        float inv = 1.0f / sum;
        for (int j = 0; j < 32; j++) swt[j][tid] *= inv;
    }
    __syncthreads();
    {
        int flat = tid * 4, h = flat >> 7, l = flat & 127;
        float4 acc = {0, 0, 0, 0};
        for (int j = 0; j < 32; j++) {
            float w = swt[j][h];
            float4 c4 = *(const float4*)&cs[j][l];
            acc.x += w * c4.x; acc.y += w * c4.y; acc.z += w * c4.z; acc.w += w * c4.w;
        }
        *(float4*)(Mo + (size_t)bid * 1024 + flat) = acc;
    }
}

// ---------------------------------------------------------------------------
// MLA absorption part 2 -> bf16 output (consumed by out-proj GEMM)
// ---------------------------------------------------------------------------
__global__ __launch_bounds__(256) void mla_out(const float* __restrict__ Mo,
                                               const float* __restrict__ uw,
                                               unsigned short* __restrict__ ob)
{
    int qt = blockIdx.x, h = blockIdx.y, tid = threadIdx.x;
    __shared__ float Ms[64][132];
    __shared__ float Us[32][129];
    {
        int r = tid >> 2, l0 = (tid & 3) * 32;
        const float* srcp = Mo + ((size_t)(qt * 64 + r)) * 1024 + h * 128 + l0;
#pragma unroll
        for (int ii = 0; ii < 8; ii++) {
            float4 v = ((const float4*)srcp)[ii];
            *(float4*)&Ms[r][l0 + ii * 4] = v;
        }
    }
    {
        int d = tid >> 3, l0 = (tid & 7) * 16;
        const float* srcp = uw + (size_t)(256 + h * DH + d) * LATD + l0;
#pragma unroll
        for (int ii = 0; ii < 4; ii++) {
            float4 v = ((const float4*)srcp)[ii];
            Us[d][l0 + ii * 4 + 0] = v.x; Us[d][l0 + ii * 4 + 1] = v.y;
            Us[d][l0 + ii * 4 + 2] = v.z; Us[d][l0 + ii * 4 + 3] = v.w;
        }
    }
    __syncthreads();
    int d = tid & 31, rg = tid >> 5;
    float acc[8] = {0, 0, 0, 0, 0, 0, 0, 0};
    for (int l = 0; l < 128; l++) {
        float u = Us[d][l];
#pragma unroll
        for (int i = 0; i < 8; i++) acc[i] += Ms[rg * 8 + i][l] * u;
    }
#pragma unroll
    for (int i = 0; i < 8; i++)
        ob[((size_t)(qt * 64 + rg * 8 + i)) * E_ + h * DH + d] = f2b(acc[i]);
}

// ---------------------------------------------------------------------------
extern "C" void kernel_launch(void* const* d_in, const int* in_sizes, int n_in,
                              void* d_out, int out_size, void* d_ws, size_t ws_size,
                              hipStream_t stream)
{
    (void)in_sizes; (void)n_in; (void)out_size; (void)ws_size;
    const float* src      = (const float*)d_in[0];
    const float* fa_in_w  = (const float*)d_in[2];
    const float* fa_in_b  = (const float*)d_in[3];
    const float* fa_out_w = (const float*)d_in[4];
    const float* fa_out_b = (const float*)d_in[5];
    const float* n1g = (const float*)d_in[6];
    const float* n1b = (const float*)d_in[7];
    const float* iqw = (const float*)d_in[8];
    const float* ikw = (const float*)d_in[9];
    const float* iow = (const float*)d_in[10];
    const float* mqw = (const float*)d_in[11];
    const float* mdw = (const float*)d_in[12];
    const float* muw = (const float*)d_in[13];
    const float* mow = (const float*)d_in[14];
    const float* n2g = (const float*)d_in[15];
    const float* n2b = (const float*)d_in[16];
    const float* l1w = (const float*)d_in[17];
    const float* l1b = (const float*)d_in[18];
    const float* l2w = (const float*)d_in[19];
    const float* l2b = (const float*)d_in[20];
    const float* n3g = (const float*)d_in[21];
    const float* n3b = (const float*)d_in[22];

    float* ws = (float*)d_ws;
    size_t off = 0;
    auto alloc = [&](size_t n) { float* p = ws + off; off += (n + 3) & ~(size_t)3; return p; };

    float* bigA = alloc((size_t)NT * 1024);   // qkv -> G -> x2 (first NT*256)
    float* Mh   = alloc((size_t)NT * 1024);   // M f32; later h1 bf16 (inside)
    float* tbuf = alloc((size_t)NT * E_);     // pre-LN buf; doubles as qb (10-11)
    float* stb  = alloc((size_t)NT * E_);     // st f32 (post-LN1, transposed)
    float* cb   = alloc((size_t)BF * SPLIT * LATD);
    unsigned short* actBF1 = (unsigned short*)alloc((size_t)NT * E_ / 2); // src16/abuf16/stb16
    unsigned short* actBF2 = (unsigned short*)alloc((size_t)NT * E_ / 2); // ob16/x216
    float* q32 = alloc((size_t)NT * 32);
    float* k32 = alloc((size_t)NT * 32);
    float* scl = alloc(128);
    int*   idxb = (int*)alloc((size_t)NT * 32);
    signed char* ki8 = (signed char*)alloc((size_t)NT * 32 / 4);
    unsigned short* w16 = (unsigned short*)alloc(950272 / 2 + 8);

    unsigned short* fa_in_w16  = w16;
    unsigned short* fa_out_w16 = fa_in_w16 + 196608;
    unsigned short* mqw16      = fa_out_w16 + 65536;
    unsigned short* mdw16      = mqw16 + 65536;
    unsigned short* mow16      = mdw16 + 32768;
    unsigned short* l1w16      = mow16 + 65536;
    unsigned short* l2w16      = l1w16 + 262144;

    float* qkv = bigA;
    float* G   = bigA;
    float* x2  = bigA;                        // LN2 out (alive after G dead)
    float* Mbuf = Mh;
    unsigned short* h116 = (unsigned short*)Mh;
    float* qb = tbuf;
    unsigned short* src16  = actBF1;
    unsigned short* abuf16 = actBF1;
    unsigned short* stb16  = actBF1;
    unsigned short* ob16   = actBF2;
    unsigned short* x216   = actBF2;

    // 0. convert weights + src to bf16
    ConvArgs ca;
    const float* segs[8] = {src, fa_in_w, fa_out_w, mqw, mdw, mow, l1w, l2w};
    unsigned short* segd[8] = {src16, fa_in_w16, fa_out_w16, mqw16, mdw16, mow16, l1w16, l2w16};
    int segn[8] = {NT * E_, 196608, 65536, 65536, 32768, 65536, 262144, 262144};
    int cum = 0;
    for (int i = 0; i < 8; i++) { ca.s[i] = segs[i]; ca.d[i] = segd[i]; cum += segn[i] / 4; ca.cum[i] = cum; }
    int totq = cum;
    convert_f2b<<<(totq + 255) / 256, 256, 0, stream>>>(ca, totq);

    dim3 blk(256);
    // 1. qkv = src @ fa_in_w^T + b
    gemm_mfma<1,0,0,0,0,0><<<dim3(6,64), blk, 0, stream>>>(src16, fa_in_w16, fa_in_b, nullptr, qkv, nullptr, NT, 768, 256);
    // 2. feature attention (S=4) -> bf16
    fa_attn<<<2048, blk, 0, stream>>>(qkv, abuf16);
    // 3. out-proj + bias + residual(src)
    gemm_mfma<1,0,1,0,0,0><<<dim3(2,64), blk, 0, stream>>>(abuf16, fa_out_w16, fa_out_b, src, tbuf, nullptr, NT, 256, 256);
    // 4. LN1, write transposed f32 + bf16
    ln_k<1,1><<<NT, dim3(64), 0, stream>>>(tbuf, n1g, n1b, stb, stb16);
    // 5. indexer projections (exact f32)
    idx_proj<<<NT, blk, 0, stream>>>(stb, iqw, ikw, q32, k32);
    // 6. scales
    idx_scales<<<96, blk, 0, stream>>>(q32, k32, scl);
    // 7. quantize k
    idx_quantk<<<(BF * SPLIT * 32) / 256, blk, 0, stream>>>(k32, scl, ki8);
    // 8. scores + top-32
    idx_score_topk<<<NT, blk, 0, stream>>>(q32, ki8, scl, iow, idxb);
    // 9. c = x_tr @ down_w^T   (train rows only)
    gemm_mfma<0,0,0,1,0,0><<<dim3(1,48), blk, 0, stream>>>(stb16, mdw16, nullptr, nullptr, cb, nullptr, BF * SPLIT, 128, 256);
    // 10. mla q projection
    gemm_mfma<0,0,0,0,0,0><<<dim3(2,64), blk, 0, stream>>>(stb16, mqw16, nullptr, nullptr, qb, nullptr, NT, 256, 256);
    // 11. G = per-head up_w(K-half)^T @ q
    mla_g<<<dim3(128,8), blk, 0, stream>>>(qb, muw, G);
    // 12. fused sparse attention -> M
    mla_attn<<<NT, blk, 0, stream>>>(G, cb, idxb, Mbuf);
    // 13. out = per-head up_w(V-half) @ M -> bf16
    mla_out<<<dim3(128,8), blk, 0, stream>>>(Mbuf, muw, ob16);
    // 14. mla out-proj + residual(stb), scatter to BRCE token rows
    gemm_mfma<0,0,1,0,1,0><<<dim3(2,64), blk, 0, stream>>>(ob16, mow16, nullptr, stb, tbuf, nullptr, NT, 256, 256);
    // 15. LN2 -> x2 f32 + bf16
    ln_k<0,1><<<NT, dim3(64), 0, stream>>>(tbuf, n2g, n2b, x2, x216);
    // 16. MLP1 + GELU -> bf16 h1
    gemm_mfma<1,1,0,0,0,1><<<dim3(8,64), blk, 0, stream>>>(x216, l1w16, l1b, nullptr, nullptr, h116, NT, MLPD, 256);
    // 17. MLP2 + bias + residual(x2)
    gemm_mfma<1,0,1,0,0,0><<<dim3(2,64), blk, 0, stream>>>(h116, l2w16, l2b, x2, tbuf, nullptr, NT, 256, MLPD);
    // 18. LN3 -> output
    ln_k<0,0><<<NT, dim3(64), 0, stream>>>(tbuf, n3g, n3b, (float*)d_out, nullptr);
}

// Round 4
// 463.111 us; speedup vs baseline: 1.6236x; 1.1419x over previous
//
#include <hip/hip_runtime.h>
#include <hip/hip_bf16.h>
#include <cmath>

#define E_ 256
#define H_ 8
#define DH 32
#define MLPD 1024
#define LATD 128
#define TOPK_ 32
#define BB 2
#define RR 1024
#define CC 4
#define NT 8192      // B*R*C tokens
#define BF 8         // B*C
#define SPLIT 768

using bf16x8 = __attribute__((ext_vector_type(8))) short;
using f32x4v = __attribute__((ext_vector_type(4))) float;

__device__ __forceinline__ unsigned short f2b(float x) {
    __hip_bfloat16 h = __float2bfloat16(x);
    return *reinterpret_cast<unsigned short*>(&h);
}

// ---------------------------------------------------------------------------
// Fused f32 -> bf16 converter for weights + src (8 segments)
// ---------------------------------------------------------------------------
struct ConvArgs {
    const float* s[8];
    unsigned short* d[8];
    int cum[8];   // cumulative quad counts (exclusive prefix ends)
};
__global__ __launch_bounds__(256) void convert_f2b(ConvArgs a, int totq)
{
    int q = blockIdx.x * 256 + threadIdx.x;
    if (q >= totq) return;
    int seg = 0;
    while (q >= a.cum[seg]) seg++;
    int lq = q - (seg ? a.cum[seg - 1] : 0);
    float4 v = ((const float4*)a.s[seg])[lq];
    ushort4 o;
    o.x = f2b(v.x); o.y = f2b(v.y); o.z = f2b(v.z); o.w = f2b(v.w);
    ((ushort4*)a.d[seg])[lq] = o;
}

// ---------------------------------------------------------------------------
// bf16 MFMA GEMM: C[M][N] = A(MxK bf16) @ W(NxK bf16)^T (+bias)(+gelu)(+res f32)
// 128x128 tile, 4 waves (2x2), each wave 64x64 via 4x4 frags of 16x16x32.
// AMAP: A-row gather (train rows). OMAP: st-row -> BRCE token row scatter.
// OUTBF: write bf16 (Ch) instead of f32 (Cf).
// ---------------------------------------------------------------------------
template<int BIAS, int GELU, int RES, int AMAP, int OMAP, int OUTBF>
__global__ __launch_bounds__(256) void gemm_mfma(
    const unsigned short* __restrict__ A, const unsigned short* __restrict__ W,
    const float* __restrict__ bias, const float* __restrict__ res,
    float* __restrict__ Cf, unsigned short* __restrict__ Ch,
    int M, int N, int K)
{
    __shared__ __align__(16) unsigned short As[128 * 40];
    __shared__ __align__(16) unsigned short Bs[128 * 40];
    const int tid = threadIdx.x;
    const int lane = tid & 63, wave = tid >> 6;
    const int wr = wave >> 1, wc = wave & 1;
    const int m0 = blockIdx.y * 128, n0 = blockIdx.x * 128;

    // staging: thread -> row ra (0..127), k-chunk kq (0 or 16)
    const int ra = tid >> 1, kq = (tid & 1) * 16;
    int am = m0 + ra;
    size_t arow = AMAP ? ((size_t)(am / SPLIT) * RR + (am % SPLIT)) : (size_t)am;
    const unsigned short* Ap = A + arow * (size_t)K + kq;
    const unsigned short* Bp = W + (size_t)(n0 + ra) * K + kq;

    f32x4v acc[4][4];
#pragma unroll
    for (int i = 0; i < 4; i++)
#pragma unroll
        for (int j = 0; j < 4; j++) acc[i][j] = (f32x4v){0.f, 0.f, 0.f, 0.f};

    const int kof = (lane >> 4) * 8;
    const int arow_lds[4] = {
        (wr * 64 + 0 * 16 + (lane & 15)) * 40 + kof,
        (wr * 64 + 1 * 16 + (lane & 15)) * 40 + kof,
        (wr * 64 + 2 * 16 + (lane & 15)) * 40 + kof,
        (wr * 64 + 3 * 16 + (lane & 15)) * 40 + kof };
    const int brow_lds[4] = {
        (wc * 64 + 0 * 16 + (lane & 15)) * 40 + kof,
        (wc * 64 + 1 * 16 + (lane & 15)) * 40 + kof,
        (wc * 64 + 2 * 16 + (lane & 15)) * 40 + kof,
        (wc * 64 + 3 * 16 + (lane & 15)) * 40 + kof };

    for (int k0 = 0; k0 < K; k0 += 32) {
        int4 va0 = *(const int4*)(Ap + k0);
        int4 va1 = *(const int4*)(Ap + k0 + 8);
        int4 vb0 = *(const int4*)(Bp + k0);
        int4 vb1 = *(const int4*)(Bp + k0 + 8);
        __syncthreads();
        *(int4*)&As[ra * 40 + kq] = va0;
        *(int4*)&As[ra * 40 + kq + 8] = va1;
        *(int4*)&Bs[ra * 40 + kq] = vb0;
        *(int4*)&Bs[ra * 40 + kq + 8] = vb1;
        __syncthreads();
        bf16x8 af[4], bf[4];
#pragma unroll
        for (int f = 0; f < 4; f++) {
            af[f] = *(const bf16x8*)&As[arow_lds[f]];
            bf[f] = *(const bf16x8*)&Bs[brow_lds[f]];
        }
#pragma unroll
        for (int fm = 0; fm < 4; fm++)
#pragma unroll
            for (int fn = 0; fn < 4; fn++)
                acc[fm][fn] = __builtin_amdgcn_mfma_f32_16x16x32_bf16(
                    af[fm], bf[fn], acc[fm][fn], 0, 0, 0);
    }

#pragma unroll
    for (int fm = 0; fm < 4; fm++) {
#pragma unroll
        for (int r = 0; r < 4; r++) {
            int row = m0 + wr * 64 + fm * 16 + ((lane >> 4) << 2) + r;
            size_t orow;
            if (OMAP) {
                int bc = row >> 10, rr = row & 1023;
                int b = bc >> 2, c = bc & 3;
                orow = ((size_t)(b * RR + rr)) * CC + c;
            } else orow = (size_t)row;
#pragma unroll
            for (int fn = 0; fn < 4; fn++) {
                int col = n0 + wc * 64 + fn * 16 + (lane & 15);
                float v = acc[fm][fn][r];
                if (BIAS) v += bias[col];
                if (GELU) v = 0.5f * v * (1.0f + erff(v * 0.70710678118654752f));
                if (RES)  v += res[(size_t)row * N + col];
                if (OUTBF) Ch[orow * (size_t)N + col] = f2b(v);
                else       Cf[orow * (size_t)N + col] = v;
            }
        }
    }
}

// ---------------------------------------------------------------------------
// Feature attention: seq len 4, per (b,r) block. Reads qkv f32, writes bf16.
// ---------------------------------------------------------------------------
__global__ __launch_bounds__(256) void fa_attn(const float* __restrict__ qkv,
                                               unsigned short* __restrict__ outb)
{
    int seq = blockIdx.x, tid = threadIdx.x;
    __shared__ float sq[4][E_], sk[4][E_], sv[4][E_];
    __shared__ float ss[H_][4][4];
    __shared__ float sw[H_][4][4];
    for (int i = 0; i < 4; i++) {
        const float* srcp = qkv + ((size_t)(seq * 4 + i)) * 768;
        for (int idx = tid; idx < 768; idx += 256) {
            float v = srcp[idx];
            if (idx < 256) sq[i][idx] = v;
            else if (idx < 512) sk[i][idx - 256] = v;
            else sv[i][idx - 512] = v;
        }
    }
    __syncthreads();
    if (tid < 128) {
        int h = tid >> 4, i = (tid >> 2) & 3, j = tid & 3;
        float s = 0;
        for (int d = 0; d < DH; d++) s += sq[i][h * DH + d] * sk[j][h * DH + d];
        ss[h][i][j] = s * 0.17677669529663688f;   // 1/sqrt(32)
    }
    __syncthreads();
    if (tid < 32) {
        int h = tid >> 2, i = tid & 3;
        float m = ss[h][i][0];
        for (int j = 1; j < 4; j++) m = fmaxf(m, ss[h][i][j]);
        float e[4], sum = 0;
        for (int j = 0; j < 4; j++) { e[j] = expf(ss[h][i][j] - m); sum += e[j]; }
        float inv = 1.0f / sum;
        for (int j = 0; j < 4; j++) sw[h][i][j] = e[j] * inv;
    }
    __syncthreads();
    int e = tid, h = e >> 5;
    for (int i = 0; i < 4; i++) {
        float o = 0;
        for (int j = 0; j < 4; j++) o += sw[h][i][j] * sv[j][e];
        outb[((size_t)(seq * 4 + i)) * E_ + e] = f2b(o);
    }
}

// ---------------------------------------------------------------------------
// LayerNorm per 256-wide row. OMAP=1: token row -> st row (transpose).
// WB=1: also write bf16 copy.
// ---------------------------------------------------------------------------
template<int OMAP, int WB>
__global__ __launch_bounds__(64) void ln_k(const float* __restrict__ in,
                                           const float* __restrict__ g,
                                           const float* __restrict__ bta,
                                           float* __restrict__ out,
                                           unsigned short* __restrict__ outh)
{
    int row = blockIdx.x, t = threadIdx.x;
    float4 v = ((const float4*)(in + (size_t)row * E_))[t];
    float s = v.x + v.y + v.z + v.w;
#pragma unroll
    for (int o = 32; o >= 1; o >>= 1) s += __shfl_xor(s, o);
    float mean = s * (1.0f / E_);
    float dx0 = v.x - mean, dx1 = v.y - mean, dx2 = v.z - mean, dx3 = v.w - mean;
    float q = dx0 * dx0 + dx1 * dx1 + dx2 * dx2 + dx3 * dx3;
#pragma unroll
    for (int o = 32; o >= 1; o >>= 1) q += __shfl_xor(q, o);
    float inv = rsqrtf(q * (1.0f / E_) + 1e-5f);
    size_t orow;
    if (OMAP == 1) {
        int b = row >> 12, r = (row >> 2) & 1023, c = row & 3;
        orow = ((size_t)(b * CC + c)) * RR + r;
    } else orow = (size_t)row;
    int c0 = t * 4;
    float4 o;
    o.x = dx0 * inv * g[c0 + 0] + bta[c0 + 0];
    o.y = dx1 * inv * g[c0 + 1] + bta[c0 + 1];
    o.z = dx2 * inv * g[c0 + 2] + bta[c0 + 2];
    o.w = dx3 * inv * g[c0 + 3] + bta[c0 + 3];
    ((float4*)(out + orow * E_))[t] = o;
    if (WB) {
        ushort4 oh; oh.x = f2b(o.x); oh.y = f2b(o.y); oh.z = f2b(o.z); oh.w = f2b(o.w);
        ((ushort4*)(outh + orow * E_))[t] = oh;
    }
}

// ---------------------------------------------------------------------------
// Indexer projections: q32 / k32 = st_row @ {idx_q_w, idx_k_w}^T  (32 each)
// ---------------------------------------------------------------------------
__global__ __launch_bounds__(256) void idx_proj(const float* __restrict__ st,
                                                const float* __restrict__ qw,
                                                const float* __restrict__ kw,
                                                float* __restrict__ q32,
                                                float* __restrict__ k32)
{
    int row = blockIdx.x, tid = threadIdx.x;
    __shared__ float sx[E_];
    sx[tid] = st[(size_t)row * E_ + tid];
    __syncthreads();
    int d = tid >> 2, sub = tid & 3;
    const float* w = (d < 32) ? (qw + (size_t)d * E_) : (kw + (size_t)(d - 32) * E_);
    float s = 0;
    for (int k = sub; k < E_; k += 4) s += w[k] * sx[k];
    s += __shfl_xor(s, 1); s += __shfl_xor(s, 2);
    if (sub == 0) {
        if (d < 32) q32[(size_t)row * 32 + d] = s;
        else        k32[(size_t)row * 32 + (d - 32)] = s;
    }
}

// ---------------------------------------------------------------------------
// Indexer scales: 96 blocks = type(0 q-train,1 q-test,2 k-train) x bf x h
// ---------------------------------------------------------------------------
__global__ __launch_bounds__(256) void idx_scales(const float* __restrict__ q32,
                                                  const float* __restrict__ k32,
                                                  float* __restrict__ scl)
{
    int id = blockIdx.x;
    int type = id / 32, bf = (id % 32) >> 2, h = id & 3;
    const float* src = (type == 2) ? k32 : q32;
    int r0 = (type == 1) ? SPLIT : 0;
    int r1 = (type == 1) ? RR : SPLIT;
    float m = 0;
    for (int r = r0 + (int)threadIdx.x; r < r1; r += 256) {
        const float* p = src + ((size_t)(bf * RR + r)) * 32 + h * 8;
        for (int dd = 0; dd < 8; dd++) m = fmaxf(m, fabsf(p[dd]));
    }
#pragma unroll
    for (int o = 32; o >= 1; o >>= 1) m = fmaxf(m, __shfl_xor(m, o));
    __shared__ float red[4];
    if ((threadIdx.x & 63) == 0) red[threadIdx.x >> 6] = m;
    __syncthreads();
    if (threadIdx.x == 0) {
        m = fmaxf(fmaxf(red[0], red[1]), fmaxf(red[2], red[3]));
        scl[id] = (m + 1e-6f) / 127.0f;
    }
}

// ---------------------------------------------------------------------------
// Quantize k (train rows only) to int8
// ---------------------------------------------------------------------------
__global__ __launch_bounds__(256) void idx_quantk(const float* __restrict__ k32,
                                                  const float* __restrict__ scl,
                                                  signed char* __restrict__ ki8)
{
    int gi = blockIdx.x * 256 + threadIdx.x;     // 0 .. 8*768*32-1
    int bf = gi / (SPLIT * 32);
    int rem = gi % (SPLIT * 32);
    int r = rem >> 5, d = rem & 31, h = d >> 3;
    float ks = scl[64 + bf * 4 + h];
    float v = k32[((size_t)(bf * RR + r)) * 32 + d];
    float qq = fminf(fmaxf(rintf(v / ks), -127.f), 127.f);
    ki8[gi] = (signed char)qq;
}

// ---------------------------------------------------------------------------
// Indexer scores + top-32. Ties -> smallest index (jax.lax.top_k semantics).
// Selection via fully-parallel rank-count over unique u64 keys:
//   stage 1: per-wave, each lane ranks its 3 candidates against the wave's
//            192 keys (LDS broadcast reads, no shuffles, no serial chain)
//   stage 2: 4x32 -> 32 rank-count merge.
// Rank order = (value desc, index asc) == jax.lax.top_k exactly.
// ---------------------------------------------------------------------------
__global__ __launch_bounds__(256) void idx_score_topk(const float* __restrict__ q32,
                                                      const signed char* __restrict__ ki8,
                                                      const float* __restrict__ scl,
                                                      const float* __restrict__ ow,
                                                      int* __restrict__ idx_out)
{
    int bid = blockIdx.x, tid = threadIdx.x;
    int bf = bid >> 10, qr = bid & 1023;
    int sel = (qr < SPLIT) ? 0 : 32;
    __shared__ float qi[32];
    __shared__ float fac[4];
    __shared__ __align__(16) unsigned long long keys[SPLIT];
    __shared__ unsigned long long warr[4][32];
    if (tid < 32) {
        int h = tid >> 3;
        float qs = scl[sel + bf * 4 + h];
        float v = q32[((size_t)bid) * 32 + tid];
        qi[tid] = fminf(fmaxf(rintf(v / qs), -127.f), 127.f);
    }
    if (tid < 4) {
        float qs = scl[sel + bf * 4 + tid];
        float ks = scl[64 + bf * 4 + tid];
        fac[tid] = __fmul_rn(qs, ks);
    }
    __syncthreads();
    float ow0 = ow[0], ow1 = ow[1], ow2 = ow[2], ow3 = ow[3];
    for (int k = tid; k < SPLIT; k += 256) {
        const int4* kp4 = (const int4*)(ki8 + ((size_t)(bf * SPLIT + k)) * 32);
        int4 w0 = kp4[0], w1 = kp4[1];
        int wd[8] = {w0.x, w0.y, w0.z, w0.w, w1.x, w1.y, w1.z, w1.w};
        float owv[4] = {ow0, ow1, ow2, ow3};
        float r = 0;
#pragma unroll
        for (int h = 0; h < 4; h++) {
            float dot = 0.f;
#pragma unroll
            for (int b = 0; b < 2; b++) {
                unsigned int w = (unsigned int)wd[h * 2 + b];
#pragma unroll
                for (int by = 0; by < 4; by++) {
                    float kv = (float)((signed char)(w >> (8 * by)));
                    dot = fmaf(qi[h * 8 + b * 4 + by], kv, dot);
                }
            }
            float sc = fmaxf(__fmul_rn(dot, fac[h]), 0.f);
            r = __fadd_rn(r, __fmul_rn(sc, owv[h]));
        }
        unsigned int bitsv = __float_as_uint(r);
        unsigned int mono = (bitsv & 0x80000000u) ? ~bitsv : (bitsv | 0x80000000u);
        if (mono == 0x7FFFFFFFu) mono = 0x80000000u;   // canonicalize -0 == +0
        keys[k] = ((unsigned long long)mono << 32) | (unsigned int)(1023 - k);
    }
    __syncthreads();
    // stage 1: per-wave rank-count top-32 (parallel, broadcast LDS reads)
    {
        int w = tid >> 6, lane = tid & 63;
        const unsigned long long* kb = &keys[w * 192];
        unsigned long long a0 = kb[lane];
        unsigned long long a1 = kb[64 + lane];
        unsigned long long a2 = kb[128 + lane];
        int r0 = 0, r1 = 0, r2 = 0;
#pragma unroll 8
        for (int j = 0; j < 192; j += 2) {
            unsigned long long k0 = kb[j], k1 = kb[j + 1];
            r0 += (int)(k0 > a0) + (int)(k1 > a0);
            r1 += (int)(k0 > a1) + (int)(k1 > a1);
            r2 += (int)(k0 > a2) + (int)(k1 > a2);
        }
        if (r0 < TOPK_) warr[w][r0] = a0;
        if (r1 < TOPK_) warr[w][r1] = a1;
        if (r2 < TOPK_) warr[w][r2] = a2;
    }
    __syncthreads();
    // stage 2: merge 4x32 -> global top-32 via rank-count
    if (tid < 128) {
        const unsigned long long mine = (&warr[0][0])[tid];
        const unsigned long long* wf = &warr[0][0];
        int r = 0;
        for (int j = 0; j < 128; j++) r += (wf[j] > mine) ? 1 : 0;
        if (r < TOPK_)
            idx_out[(size_t)bid * TOPK_ + r] = 1023 - (int)(unsigned int)(mine & 0xFFFFFFFFull);
    }
}

// ---------------------------------------------------------------------------
// MLA absorption part 1: G[q][h][l] = sum_d qb[q][h*32+d] * up_w[h*32+d][l]
// ---------------------------------------------------------------------------
__global__ __launch_bounds__(256) void mla_g(const float* __restrict__ qb,
                                             const float* __restrict__ uw,
                                             float* __restrict__ G)
{
    int qt = blockIdx.x, h = blockIdx.y, tid = threadIdx.x;
    __shared__ float Qs[64][33];
    __shared__ float Us[32][132];
    {
        int r = tid >> 2, c0 = (tid & 3) * 8;
        const float* srcp = qb + ((size_t)(qt * 64 + r)) * E_ + h * DH + c0;
        float4 a = ((const float4*)srcp)[0];
        float4 b = ((const float4*)srcp)[1];
        Qs[r][c0 + 0] = a.x; Qs[r][c0 + 1] = a.y; Qs[r][c0 + 2] = a.z; Qs[r][c0 + 3] = a.w;
        Qs[r][c0 + 4] = b.x; Qs[r][c0 + 5] = b.y; Qs[r][c0 + 6] = b.z; Qs[r][c0 + 7] = b.w;
    }
    {
        int d = tid >> 3, l0 = (tid & 7) * 16;
        const float* srcp = uw + (size_t)(h * DH + d) * LATD + l0;
#pragma unroll
        for (int ii = 0; ii < 4; ii++) {
            float4 v = ((const float4*)srcp)[ii];
            *(float4*)&Us[d][l0 + ii * 4] = v;
        }
    }
    __syncthreads();
    int rg = tid >> 5, l = (tid & 31) * 4;
    float acc[8][4];
#pragma unroll
    for (int i = 0; i < 8; i++)
#pragma unroll
        for (int j = 0; j < 4; j++) acc[i][j] = 0.f;
    for (int d = 0; d < DH; d++) {
        float4 u = *(const float4*)&Us[d][l];
#pragma unroll
        for (int i = 0; i < 8; i++) {
            float qv = Qs[rg * 8 + i][d];
            acc[i][0] += qv * u.x; acc[i][1] += qv * u.y;
            acc[i][2] += qv * u.z; acc[i][3] += qv * u.w;
        }
    }
#pragma unroll
    for (int i = 0; i < 8; i++) {
        float4 o = {acc[i][0], acc[i][1], acc[i][2], acc[i][3]};
        *(float4*)(G + ((size_t)(qt * 64 + rg * 8 + i)) * 1024 + h * 128 + l) = o;
    }
}

// ---------------------------------------------------------------------------
// Fused sparse MLA attention per (bf, q)
// ---------------------------------------------------------------------------
__global__ __launch_bounds__(256) void mla_attn(const float* __restrict__ G,
                                                const float* __restrict__ cb,
                                                const int* __restrict__ idxb,
                                                float* __restrict__ Mo)
{
    int bid = blockIdx.x, tid = threadIdx.x;
    int bf = bid >> 10;
    __shared__ float cs[32][132];
    __shared__ float gs[8][132];
    __shared__ float swt[32][8];
    __shared__ int sidx[32];
    if (tid < 32) sidx[tid] = idxb[(size_t)bid * 32 + tid];
    {
        int flat = tid * 4, h = flat >> 7, l = flat & 127;
        float4 gv = *(const float4*)(G + (size_t)bid * 1024 + flat);
        *(float4*)&gs[h][l] = gv;
    }
    __syncthreads();
    {
        int j = tid >> 3, l0 = (tid & 7) * 16;
        const float* srcp = cb + ((size_t)(bf * SPLIT + sidx[j])) * LATD + l0;
#pragma unroll
        for (int ii = 0; ii < 4; ii++) {
            float4 vv = ((const float4*)srcp)[ii];
            *(float4*)&cs[j][l0 + ii * 4] = vv;
        }
    }
    __syncthreads();
    {
        int j = tid >> 3, h = tid & 7;
        float s = 0;
#pragma unroll
        for (int lb = 0; lb < 32; lb++) {
            float4 c4 = *(const float4*)&cs[j][lb * 4];
            float4 g4 = *(const float4*)&gs[h][lb * 4];
            s += c4.x * g4.x + c4.y * g4.y + c4.z * g4.z + c4.w * g4.w;
        }
        swt[j][h] = s * 0.17677669529663688f;
    }
    __syncthreads();
    if (tid < 8) {
        float m = swt[0][tid];
        for (int j = 1; j < 32; j++) m = fmaxf(m, swt[j][tid]);
        float sum = 0;
        for (int j = 0; j < 32; j++) { float e = expf(swt[j][tid] - m); swt[j][tid] = e; sum += e; }
        float inv = 1.0f / sum;
        for (int j = 0; j < 32; j++) swt[j][tid] *= inv;
    }
    __syncthreads();
    {
        int flat = tid * 4, h = flat >> 7, l = flat & 127;
        float4 acc = {0, 0, 0, 0};
        for (int j = 0; j < 32; j++) {
            float w = swt[j][h];
            float4 c4 = *(const float4*)&cs[j][l];
            acc.x += w * c4.x; acc.y += w * c4.y; acc.z += w * c4.z; acc.w += w * c4.w;
        }
        *(float4*)(Mo + (size_t)bid * 1024 + flat) = acc;
    }
}

// ---------------------------------------------------------------------------
// MLA absorption part 2 -> bf16 output (consumed by out-proj GEMM)
// ---------------------------------------------------------------------------
__global__ __launch_bounds__(256) void mla_out(const float* __restrict__ Mo,
                                               const float* __restrict__ uw,
                                               unsigned short* __restrict__ ob)
{
    int qt = blockIdx.x, h = blockIdx.y, tid = threadIdx.x;
    __shared__ float Ms[64][132];
    __shared__ float Us[32][129];
    {
        int r = tid >> 2, l0 = (tid & 3) * 32;
        const float* srcp = Mo + ((size_t)(qt * 64 + r)) * 1024 + h * 128 + l0;
#pragma unroll
        for (int ii = 0; ii < 8; ii++) {
            float4 v = ((const float4*)srcp)[ii];
            *(float4*)&Ms[r][l0 + ii * 4] = v;
        }
    }
    {
        int d = tid >> 3, l0 = (tid & 7) * 16;
        const float* srcp = uw + (size_t)(256 + h * DH + d) * LATD + l0;
#pragma unroll
        for (int ii = 0; ii < 4; ii++) {
            float4 v = ((const float4*)srcp)[ii];
            Us[d][l0 + ii * 4 + 0] = v.x; Us[d][l0 + ii * 4 + 1] = v.y;
            Us[d][l0 + ii * 4 + 2] = v.z; Us[d][l0 + ii * 4 + 3] = v.w;
        }
    }
    __syncthreads();
    int d = tid & 31, rg = tid >> 5;
    float acc[8] = {0, 0, 0, 0, 0, 0, 0, 0};
    for (int l = 0; l < 128; l++) {
        float u = Us[d][l];
#pragma unroll
        for (int i = 0; i < 8; i++) acc[i] += Ms[rg * 8 + i][l] * u;
    }
#pragma unroll
    for (int i = 0; i < 8; i++)
        ob[((size_t)(qt * 64 + rg * 8 + i)) * E_ + h * DH + d] = f2b(acc[i]);
}

// ---------------------------------------------------------------------------
extern "C" void kernel_launch(void* const* d_in, const int* in_sizes, int n_in,
                              void* d_out, int out_size, void* d_ws, size_t ws_size,
                              hipStream_t stream)
{
    (void)in_sizes; (void)n_in; (void)out_size; (void)ws_size;
    const float* src      = (const float*)d_in[0];
    const float* fa_in_w  = (const float*)d_in[2];
    const float* fa_in_b  = (const float*)d_in[3];
    const float* fa_out_w = (const float*)d_in[4];
    const float* fa_out_b = (const float*)d_in[5];
    const float* n1g = (const float*)d_in[6];
    const float* n1b = (const float*)d_in[7];
    const float* iqw = (const float*)d_in[8];
    const float* ikw = (const float*)d_in[9];
    const float* iow = (const float*)d_in[10];
    const float* mqw = (const float*)d_in[11];
    const float* mdw = (const float*)d_in[12];
    const float* muw = (const float*)d_in[13];
    const float* mow = (const float*)d_in[14];
    const float* n2g = (const float*)d_in[15];
    const float* n2b = (const float*)d_in[16];
    const float* l1w = (const float*)d_in[17];
    const float* l1b = (const float*)d_in[18];
    const float* l2w = (const float*)d_in[19];
    const float* l2b = (const float*)d_in[20];
    const float* n3g = (const float*)d_in[21];
    const float* n3b = (const float*)d_in[22];

    float* ws = (float*)d_ws;
    size_t off = 0;
    auto alloc = [&](size_t n) { float* p = ws + off; off += (n + 3) & ~(size_t)3; return p; };

    float* bigA = alloc((size_t)NT * 1024);   // qkv -> G -> x2 (first NT*256)
    float* Mh   = alloc((size_t)NT * 1024);   // M f32; later h1 bf16 (inside)
    float* tbuf = alloc((size_t)NT * E_);     // pre-LN buf; doubles as qb (10-11)
    float* stb  = alloc((size_t)NT * E_);     // st f32 (post-LN1, transposed)
    float* cb   = alloc((size_t)BF * SPLIT * LATD);
    unsigned short* actBF1 = (unsigned short*)alloc((size_t)NT * E_ / 2); // src16/abuf16/stb16
    unsigned short* actBF2 = (unsigned short*)alloc((size_t)NT * E_ / 2); // ob16/x216
    float* q32 = alloc((size_t)NT * 32);
    float* k32 = alloc((size_t)NT * 32);
    float* scl = alloc(128);
    int*   idxb = (int*)alloc((size_t)NT * 32);
    signed char* ki8 = (signed char*)alloc((size_t)NT * 32 / 4);
    unsigned short* w16 = (unsigned short*)alloc(950272 / 2 + 8);

    unsigned short* fa_in_w16  = w16;
    unsigned short* fa_out_w16 = fa_in_w16 + 196608;
    unsigned short* mqw16      = fa_out_w16 + 65536;
    unsigned short* mdw16      = mqw16 + 65536;
    unsigned short* mow16      = mdw16 + 32768;
    unsigned short* l1w16      = mow16 + 65536;
    unsigned short* l2w16      = l1w16 + 262144;

    float* qkv = bigA;
    float* G   = bigA;
    float* x2  = bigA;                        // LN2 out (alive after G dead)
    float* Mbuf = Mh;
    unsigned short* h116 = (unsigned short*)Mh;
    float* qb = tbuf;
    unsigned short* src16  = actBF1;
    unsigned short* abuf16 = actBF1;
    unsigned short* stb16  = actBF1;
    unsigned short* ob16   = actBF2;
    unsigned short* x216   = actBF2;

    // 0. convert weights + src to bf16
    ConvArgs ca;
    const float* segs[8] = {src, fa_in_w, fa_out_w, mqw, mdw, mow, l1w, l2w};
    unsigned short* segd[8] = {src16, fa_in_w16, fa_out_w16, mqw16, mdw16, mow16, l1w16, l2w16};
    int segn[8] = {NT * E_, 196608, 65536, 65536, 32768, 65536, 262144, 262144};
    int cum = 0;
    for (int i = 0; i < 8; i++) { ca.s[i] = segs[i]; ca.d[i] = segd[i]; cum += segn[i] / 4; ca.cum[i] = cum; }
    int totq = cum;
    convert_f2b<<<(totq + 255) / 256, 256, 0, stream>>>(ca, totq);

    dim3 blk(256);
    // 1. qkv = src @ fa_in_w^T + b
    gemm_mfma<1,0,0,0,0,0><<<dim3(6,64), blk, 0, stream>>>(src16, fa_in_w16, fa_in_b, nullptr, qkv, nullptr, NT, 768, 256);
    // 2. feature attention (S=4) -> bf16
    fa_attn<<<2048, blk, 0, stream>>>(qkv, abuf16);
    // 3. out-proj + bias + residual(src)
    gemm_mfma<1,0,1,0,0,0><<<dim3(2,64), blk, 0, stream>>>(abuf16, fa_out_w16, fa_out_b, src, tbuf, nullptr, NT, 256, 256);
    // 4. LN1, write transposed f32 + bf16
    ln_k<1,1><<<NT, dim3(64), 0, stream>>>(tbuf, n1g, n1b, stb, stb16);
    // 5. indexer projections (exact f32)
    idx_proj<<<NT, blk, 0, stream>>>(stb, iqw, ikw, q32, k32);
    // 6. scales
    idx_scales<<<96, blk, 0, stream>>>(q32, k32, scl);
    // 7. quantize k
    idx_quantk<<<(BF * SPLIT * 32) / 256, blk, 0, stream>>>(k32, scl, ki8);
    // 8. scores + top-32
    idx_score_topk<<<NT, blk, 0, stream>>>(q32, ki8, scl, iow, idxb);
    // 9. c = x_tr @ down_w^T   (train rows only)
    gemm_mfma<0,0,0,1,0,0><<<dim3(1,48), blk, 0, stream>>>(stb16, mdw16, nullptr, nullptr, cb, nullptr, BF * SPLIT, 128, 256);
    // 10. mla q projection
    gemm_mfma<0,0,0,0,0,0><<<dim3(2,64), blk, 0, stream>>>(stb16, mqw16, nullptr, nullptr, qb, nullptr, NT, 256, 256);
    // 11. G = per-head up_w(K-half)^T @ q
    mla_g<<<dim3(128,8), blk, 0, stream>>>(qb, muw, G);
    // 12. fused sparse attention -> M
    mla_attn<<<NT, blk, 0, stream>>>(G, cb, idxb, Mbuf);
    // 13. out = per-head up_w(V-half) @ M -> bf16
    mla_out<<<dim3(128,8), blk, 0, stream>>>(Mbuf, muw, ob16);
    // 14. mla out-proj + residual(stb), scatter to BRCE token rows
    gemm_mfma<0,0,1,0,1,0><<<dim3(2,64), blk, 0, stream>>>(ob16, mow16, nullptr, stb, tbuf, nullptr, NT, 256, 256);
    // 15. LN2 -> x2 f32 + bf16
    ln_k<0,1><<<NT, dim3(64), 0, stream>>>(tbuf, n2g, n2b, x2, x216);
    // 16. MLP1 + GELU -> bf16 h1
    gemm_mfma<1,1,0,0,0,1><<<dim3(8,64), blk, 0, stream>>>(x216, l1w16, l1b, nullptr, nullptr, h116, NT, MLPD, 256);
    // 17. MLP2 + bias + residual(x2)
    gemm_mfma<1,0,1,0,0,0><<<dim3(2,64), blk, 0, stream>>>(h116, l2w16, l2b, x2, tbuf, nullptr, NT, 256, MLPD);
    // 18. LN3 -> output
    ln_k<0,0><<<NT, dim3(64), 0, stream>>>(tbuf, n3g, n3b, (float*)d_out, nullptr);
}